// Round 1
// baseline (824.389 us; speedup 1.0000x reference)
//
#include <hip/hip_runtime.h>
#include <hip/hip_bf16.h>

#define T_SEQ 2048
#define DMODEL 2048
#define NHEADS 16
#define HDIM 128
#define FFN_D 8192
#define RMS_EPS 1.1920929e-7f

typedef __hip_bfloat16 bf16;
using bf16x8 = __attribute__((ext_vector_type(8))) short;
using f32x4  = __attribute__((ext_vector_type(4))) float;

__device__ __forceinline__ float bf2f(bf16 v) { return __bfloat162float(v); }
__device__ __forceinline__ bf16  f2bf(float v) { return __float2bfloat16(v); }

__device__ __forceinline__ void async16(const void* g, void* l) {
    __builtin_amdgcn_global_load_lds(
        (const __attribute__((address_space(1))) void*)g,
        (__attribute__((address_space(3))) void*)l,
        16, 0, 0);
}

// ---------------- RMSNorm: fp32 row -> bf16 row ----------------
__global__ __launch_bounds__(256) void rmsnorm_k(const float* __restrict__ x,
                                                 bf16* __restrict__ out) {
    int row = blockIdx.x;
    const float* xr = x + (size_t)row * DMODEL;
    int t = threadIdx.x;
    float v[8];
    float ss = 0.f;
#pragma unroll
    for (int i = 0; i < 8; ++i) { v[i] = xr[t + i * 256]; ss += v[i] * v[i]; }
#pragma unroll
    for (int o = 32; o > 0; o >>= 1) ss += __shfl_xor(ss, o, 64);
    __shared__ float wsum[4];
    int wave = t >> 6;
    if ((t & 63) == 0) wsum[wave] = ss;
    __syncthreads();
    ss = wsum[0] + wsum[1] + wsum[2] + wsum[3];
    float sc = rsqrtf(ss * (1.0f / DMODEL) + RMS_EPS);
    bf16* orow = out + (size_t)row * DMODEL;
#pragma unroll
    for (int i = 0; i < 8; ++i) orow[t + i * 256] = f2bf(v[i] * sc);
}

// ---------------- scale+convert fp32 -> bf16 ----------------
__global__ __launch_bounds__(256) void convert_k(const float* __restrict__ in,
                                                 bf16* __restrict__ out,
                                                 const float* __restrict__ lam, int li,
                                                 size_t n) {
    float s = lam ? lam[li] : 1.0f;
    size_t i = (size_t)blockIdx.x * 1024 + (size_t)threadIdx.x * 4;
    if (i + 3 < n) {
        float4 f = *(const float4*)(in + i);
        bf16 h0 = f2bf(f.x * s), h1 = f2bf(f.y * s), h2 = f2bf(f.z * s), h3 = f2bf(f.w * s);
        short4 o;
        o.x = *(short*)&h0; o.y = *(short*)&h1; o.z = *(short*)&h2; o.w = *(short*)&h3;
        *(short4*)((short*)out + i) = o;
    }
}

// ---------------- transpose + convert: c_proj (FFN x D) -> (D x FFN) bf16 ----------------
__global__ __launch_bounds__(256) void transpose_convert_k(const float* __restrict__ in,
                                                           bf16* __restrict__ out) {
    __shared__ float tile[32][33];
    int f0 = blockIdx.x * 32;
    int d0 = blockIdx.y * 32;
    int tx = threadIdx.x & 31, ty = threadIdx.x >> 5;
#pragma unroll
    for (int i = 0; i < 32; i += 8)
        tile[ty + i][tx] = in[(size_t)(f0 + ty + i) * DMODEL + d0 + tx];
    __syncthreads();
#pragma unroll
    for (int i = 0; i < 32; i += 8)
        out[(size_t)(d0 + ty + i) * FFN_D + f0 + tx] = f2bf(tile[tx][ty + i]);
}

// ---------------- GEMM: C(MxN) = A(MxK) * B(NxK)^T, bf16 inputs, fp32 acc ----------------
// EPI: 0 = fp32 out, 1 = fp32 out + addsrc, 2 = bf16 out with relu^2
template <int EPI>
__global__ __launch_bounds__(256) void gemm_bt(const bf16* __restrict__ A,
                                               const bf16* __restrict__ B,
                                               float* __restrict__ Cf,
                                               bf16* __restrict__ Cb,
                                               const float* __restrict__ addsrc,
                                               int M, int N, int K) {
    __shared__ alignas(16) short lA[128 * 32];
    __shared__ alignas(16) short lB[128 * 32];
    int t = threadIdx.x;
    int wave = t >> 6, lane = t & 63;
    int m0 = blockIdx.y * 128, n0 = blockIdx.x * 128;
    int wm = (wave >> 1) * 64, wn = (wave & 1) * 64;
    int lr = lane & 15, kq = lane >> 4;

    f32x4 acc[4][4];
#pragma unroll
    for (int i = 0; i < 4; ++i)
#pragma unroll
        for (int j = 0; j < 4; ++j) acc[i][j] = (f32x4)0.0f;

    int srow = wave * 16 + (lane >> 2);
    int scol = (lane & 3) * 8;
    const bf16* gA0 = A + (size_t)(m0 + srow) * K + scol;
    const bf16* gA1 = A + (size_t)(m0 + 64 + srow) * K + scol;
    const bf16* gB0 = B + (size_t)(n0 + srow) * K + scol;
    const bf16* gB1 = B + (size_t)(n0 + 64 + srow) * K + scol;
    short* lA0 = lA + (wave * 16) * 32;
    short* lA1 = lA + (64 + wave * 16) * 32;
    short* lB0 = lB + (wave * 16) * 32;
    short* lB1 = lB + (64 + wave * 16) * 32;

    for (int k0 = 0; k0 < K; k0 += 32) {
        async16(gA0 + k0, lA0);
        async16(gA1 + k0, lA1);
        async16(gB0 + k0, lB0);
        async16(gB1 + k0, lB1);
        __syncthreads();
        bf16x8 af[4], bfr[4];
#pragma unroll
        for (int mi = 0; mi < 4; ++mi)
            af[mi] = *(const bf16x8*)&lA[(wm + mi * 16 + lr) * 32 + kq * 8];
#pragma unroll
        for (int ni = 0; ni < 4; ++ni)
            bfr[ni] = *(const bf16x8*)&lB[(wn + ni * 16 + lr) * 32 + kq * 8];
#pragma unroll
        for (int mi = 0; mi < 4; ++mi)
#pragma unroll
            for (int ni = 0; ni < 4; ++ni)
                acc[mi][ni] = __builtin_amdgcn_mfma_f32_16x16x32_bf16(af[mi], bfr[ni], acc[mi][ni], 0, 0, 0);
        __syncthreads();
    }

#pragma unroll
    for (int mi = 0; mi < 4; ++mi)
#pragma unroll
        for (int ni = 0; ni < 4; ++ni)
#pragma unroll
            for (int r = 0; r < 4; ++r) {
                int row = m0 + wm + mi * 16 + kq * 4 + r;
                int col = n0 + wn + ni * 16 + lr;
                float v = acc[mi][ni][r];
                size_t idx = (size_t)row * N + col;
                if (EPI == 0) {
                    Cf[idx] = v;
                } else if (EPI == 1) {
                    Cf[idx] = addsrc[idx] + v;
                } else {
                    float rv = fmaxf(v, 0.f);
                    Cb[idx] = f2bf(rv * rv);
                }
            }
}

// ---------------- attention + ve gates (sigmoid of xn . w_h) ----------------
__global__ __launch_bounds__(256) void gates_k(const bf16* __restrict__ xn,
                                               const float* __restrict__ agw,
                                               const float* __restrict__ vgw,
                                               float* __restrict__ ag,
                                               float* __restrict__ vg) {
    int trow = blockIdx.x;
    __shared__ float xr[DMODEL];
    int t = threadIdx.x;
#pragma unroll
    for (int i = 0; i < 8; ++i) xr[t + i * 256] = bf2f(xn[(size_t)trow * DMODEL + t + i * 256]);
    __syncthreads();
    int wave = t >> 6, lane = t & 63;
#pragma unroll
    for (int hh = 0; hh < 4; ++hh) {
        int h = wave * 4 + hh;
        float sa = 0.f, sv = 0.f;
        for (int d = lane; d < DMODEL; d += 64) {
            float xv = xr[d];
            sa += xv * agw[h * DMODEL + d];
            sv += xv * vgw[h * DMODEL + d];
        }
#pragma unroll
        for (int o = 32; o > 0; o >>= 1) {
            sa += __shfl_xor(sa, o, 64);
            sv += __shfl_xor(sv, o, 64);
        }
        if (lane == 0) {
            ag[trow * NHEADS + h] = 1.f / (1.f + __expf(-sa));
            vg[trow * NHEADS + h] = 1.f / (1.f + __expf(-sv));
        }
    }
}

// ---------------- qkv post-processing: per-head rmsnorm + rope; v += gate*ve ----------------
// outputs: qp (H,T,HD) bf16 ; kp (H,T,HD) bf16 (rotated, UNshifted) ; vp (H,HD,T) bf16
__global__ __launch_bounds__(64) void qkvproc_k(const float* __restrict__ qkv,
                                                const float* __restrict__ cosb,
                                                const float* __restrict__ sinb,
                                                const float* __restrict__ ve,
                                                const float* __restrict__ vg,
                                                bf16* __restrict__ qp,
                                                bf16* __restrict__ kp,
                                                bf16* __restrict__ vp) {
    int trow = blockIdx.x, h = blockIdx.y, lane = threadIdx.x;
    const float* base = qkv + (size_t)trow * (3 * DMODEL);
    float q0 = base[h * HDIM + lane], q1 = base[h * HDIM + lane + 64];
    float k0 = base[DMODEL + h * HDIM + lane], k1 = base[DMODEL + h * HDIM + lane + 64];
    float v0 = base[2 * DMODEL + h * HDIM + lane], v1 = base[2 * DMODEL + h * HDIM + lane + 64];
    float ssq = q0 * q0 + q1 * q1, ssk = k0 * k0 + k1 * k1;
#pragma unroll
    for (int o = 32; o > 0; o >>= 1) {
        ssq += __shfl_xor(ssq, o, 64);
        ssk += __shfl_xor(ssk, o, 64);
    }
    float scq = rsqrtf(ssq * (1.f / HDIM) + RMS_EPS);
    float sck = rsqrtf(ssk * (1.f / HDIM) + RMS_EPS);
    q0 *= scq; q1 *= scq; k0 *= sck; k1 *= sck;
    float c = cosb[trow * 64 + lane], s = sinb[trow * 64 + lane];
    float qo0 = q0 * c + q1 * s, qo1 = -q0 * s + q1 * c;
    float ko0 = k0 * c + k1 * s, ko1 = -k0 * s + k1 * c;
    size_t o = ((size_t)h * T_SEQ + trow) * HDIM + lane;
    qp[o] = f2bf(qo0); qp[o + 64] = f2bf(qo1);
    kp[o] = f2bf(ko0); kp[o + 64] = f2bf(ko1);
    float g = vg[trow * NHEADS + h];
    v0 += g * ve[(size_t)trow * DMODEL + h * HDIM + lane];
    v1 += g * ve[(size_t)trow * DMODEL + h * HDIM + lane + 64];
    vp[((size_t)h * HDIM + lane) * T_SEQ + trow] = f2bf(v0);
    vp[((size_t)h * HDIM + lane + 64) * T_SEQ + trow] = f2bf(v1);
}

// ---------------- flash attention (doc-masked causal), key-shift during staging ----------------
__global__ __launch_bounds__(256) void fattn_k(const bf16* __restrict__ qp,
                                               const bf16* __restrict__ kp,
                                               const bf16* __restrict__ vp,
                                               const int* __restrict__ docs,
                                               const float* __restrict__ scale_p,
                                               const float* __restrict__ ag,
                                               const int* __restrict__ keyoff,
                                               bf16* __restrict__ y) {
    int h = blockIdx.y;
    int q0 = blockIdx.x * 64;
    int t = threadIdx.x, wave = t >> 6, lane = t & 63;
    int lr = lane & 15, kq = lane >> 4;
    __shared__ alignas(16) short sQ[64 * 128];
    __shared__ alignas(16) short sK[64 * 128];
    __shared__ alignas(16) short sV[128 * 64];
    __shared__ alignas(16) short sP[4][16 * 64];

    const bf16* qh = qp + (size_t)h * T_SEQ * HDIM;
    const bf16* kh = kp + (size_t)h * T_SEQ * HDIM;
    const bf16* vh = vp + (size_t)h * HDIM * T_SEQ;
    int ko = keyoff[0];

    // stage Q (64 x 128)
    {
        int srow = wave * 4 + (lane >> 4);
        int scq = (lane & 15) * 8;
#pragma unroll
        for (int i = 0; i < 4; ++i)
            async16(qh + (size_t)(q0 + i * 16 + srow) * HDIM + scq, &sQ[(i * 16 + wave * 4) * HDIM]);
    }
    __syncthreads();
    bf16x8 qf[4];
#pragma unroll
    for (int kk = 0; kk < 4; ++kk)
        qf[kk] = *(const bf16x8*)&sQ[(wave * 16 + lr) * HDIM + kk * 32 + kq * 8];

    float scl = scale_p[0];
    int myq[4], mydoc[4];
#pragma unroll
    for (int r = 0; r < 4; ++r) {
        myq[r] = q0 + wave * 16 + kq * 4 + r;
        mydoc[r] = docs[myq[r]];
    }
    float m_i[4], l_i[4];
#pragma unroll
    for (int r = 0; r < 4; ++r) { m_i[r] = -1e30f; l_i[r] = 0.f; }
    f32x4 oacc[8];
#pragma unroll
    for (int i = 0; i < 8; ++i) oacc[i] = (f32x4)0.f;

    // doc skip: first s with docs[s] == docs[q0]
    int dq0 = docs[q0];
    int lo = 0, hi = q0;
    while (lo < hi) { int mid = (lo + hi) >> 1; if (docs[mid] < dq0) lo = mid + 1; else hi = mid; }
    int s_begin = lo & ~63;

    for (int s0 = s_begin; s0 <= q0; s0 += 64) {
        // stage K (64 x 128) with key-shift applied per 16B chunk
        {
            int rbase = wave * 4 + (lane >> 4);
            int scq = (lane & 15) * 8;
            int band = (scq >> 5) & 1;
#pragma unroll
            for (int i = 0; i < 4; ++i) {
                int g = s0 + i * 16 + rbase;
                int ts = (ko && band && g > 0) ? g - 1 : g;
                async16(kh + (size_t)ts * HDIM + scq, &sK[(i * 16 + wave * 4) * HDIM]);
            }
            // stage V^T (128 x 64)
            int vrow = wave * 8 + (lane >> 3);
            int vcq = (lane & 7) * 8;
#pragma unroll
            for (int i = 0; i < 4; ++i)
                async16(vh + (size_t)(i * 32 + vrow) * T_SEQ + s0 + vcq, &sV[(i * 32 + wave * 8) * 64]);
        }
        __syncthreads();

        // S = Q K^T
        f32x4 sc[4];
#pragma unroll
        for (int ni = 0; ni < 4; ++ni) {
            sc[ni] = (f32x4)0.f;
#pragma unroll
            for (int kk = 0; kk < 4; ++kk) {
                bf16x8 bfrag = *(const bf16x8*)&sK[(ni * 16 + lr) * HDIM + kk * 32 + kq * 8];
                sc[ni] = __builtin_amdgcn_mfma_f32_16x16x32_bf16(qf[kk], bfrag, sc[ni], 0, 0, 0);
            }
        }
        // mask + scale
        float pv[4][4];
        float mt[4];
#pragma unroll
        for (int r = 0; r < 4; ++r) mt[r] = -1e30f;
#pragma unroll
        for (int ni = 0; ni < 4; ++ni) {
            int scol = s0 + ni * 16 + lr;
            int sdoc = docs[scol];
#pragma unroll
            for (int r = 0; r < 4; ++r) {
                float v = sc[ni][r] * scl;
                if (scol > myq[r] || sdoc != mydoc[r]) v = -1e30f;
                pv[ni][r] = v;
                mt[r] = fmaxf(mt[r], v);
            }
        }
#pragma unroll
        for (int r = 0; r < 4; ++r) {
#pragma unroll
            for (int o = 1; o < 16; o <<= 1) mt[r] = fmaxf(mt[r], __shfl_xor(mt[r], o, 64));
        }
        float alpha[4], rsum[4];
#pragma unroll
        for (int r = 0; r < 4; ++r) {
            float mnew = fmaxf(m_i[r], mt[r]);
            alpha[r] = __expf(m_i[r] - mnew);
            m_i[r] = mnew;
            rsum[r] = 0.f;
        }
#pragma unroll
        for (int ni = 0; ni < 4; ++ni)
#pragma unroll
            for (int r = 0; r < 4; ++r) {
                float p = __expf(pv[ni][r] - m_i[r]);
                pv[ni][r] = p;
                rsum[r] += p;
            }
#pragma unroll
        for (int r = 0; r < 4; ++r) {
#pragma unroll
            for (int o = 1; o < 16; o <<= 1) rsum[r] += __shfl_xor(rsum[r], o, 64);
            l_i[r] = l_i[r] * alpha[r] + rsum[r];
        }
#pragma unroll
        for (int i = 0; i < 8; ++i)
#pragma unroll
            for (int r = 0; r < 4; ++r) oacc[i][r] *= alpha[r];

        // P (C-layout) -> LDS -> A-layout
#pragma unroll
        for (int ni = 0; ni < 4; ++ni)
#pragma unroll
            for (int r = 0; r < 4; ++r) {
                bf16 b = f2bf(pv[ni][r]);
                sP[wave][(kq * 4 + r) * 64 + ni * 16 + lr] = *(short*)&b;
            }
        bf16x8 pf[2];
#pragma unroll
        for (int kk = 0; kk < 2; ++kk)
            pf[kk] = *(const bf16x8*)&sP[wave][lr * 64 + kk * 32 + kq * 8];
#pragma unroll
        for (int oi = 0; oi < 8; ++oi) {
#pragma unroll
            for (int kk = 0; kk < 2; ++kk) {
                bf16x8 vfrag = *(const bf16x8*)&sV[(oi * 16 + lr) * 64 + kk * 32 + kq * 8];
                oacc[oi] = __builtin_amdgcn_mfma_f32_16x16x32_bf16(pf[kk], vfrag, oacc[oi], 0, 0, 0);
            }
        }
        __syncthreads();
    }

    // epilogue: y[t, h*128+d] = gate * O / l
#pragma unroll
    for (int r = 0; r < 4; ++r) {
        int row = myq[r];
        float g = ag[row * NHEADS + h];
        float inv = g / l_i[r];
#pragma unroll
        for (int oi = 0; oi < 8; ++oi)
            y[(size_t)row * DMODEL + h * HDIM + oi * 16 + lr] = f2bf(oacc[oi][r] * inv);
    }
}

extern "C" void kernel_launch(void* const* d_in, const int* in_sizes, int n_in,
                              void* d_out, int out_size, void* d_ws, size_t ws_size,
                              hipStream_t stream) {
    (void)in_sizes; (void)n_in; (void)out_size; (void)ws_size;
    const float* x      = (const float*)d_in[0];
    const float* ve     = (const float*)d_in[1];
    const float* qkvo_w = (const float*)d_in[2];
    const float* agw    = (const float*)d_in[3];
    const float* vgw    = (const float*)d_in[4];
    const float* c_fc   = (const float*)d_in[5];
    const float* c_proj = (const float*)d_in[6];
    const float* lam    = (const float*)d_in[7];
    const float* cosb   = (const float*)d_in[8];
    const float* sinb   = (const float*)d_in[9];
    const float* ascale = (const float*)d_in[10];
    const int*   docs   = (const int*)d_in[11];
    const int*   keyoff = (const int*)d_in[12];
    float* out = (float*)d_out;

    char* ws = (char*)d_ws;
    size_t off = 0;
    auto alloc = [&](size_t bytes) {
        char* p = ws + off;
        off += (bytes + 255) & ~(size_t)255;
        return p;
    };
    bf16*  xn     = (bf16*)alloc((size_t)T_SEQ * DMODEL * 2);
    bf16*  wqkv   = (bf16*)alloc((size_t)3 * DMODEL * DMODEL * 2);
    bf16*  wo     = (bf16*)alloc((size_t)DMODEL * DMODEL * 2);
    bf16*  wfc    = (bf16*)alloc((size_t)FFN_D * DMODEL * 2);
    bf16*  wprojT = (bf16*)alloc((size_t)DMODEL * FFN_D * 2);
    char*  qkvreg = alloc((size_t)T_SEQ * 3 * DMODEL * 4);   // 50.3 MB region
    float* qkv    = (float*)qkvreg;                          // steps 3-5
    bf16*  hbuf   = (bf16*)qkvreg;                           // step 10-11 (33.5 MB)
    bf16*  ybuf   = (bf16*)(qkvreg + (size_t)T_SEQ * FFN_D * 2); // step 7-8 (8.4 MB, fits)
    bf16*  qp     = (bf16*)alloc((size_t)NHEADS * T_SEQ * HDIM * 2);
    bf16*  kp     = (bf16*)alloc((size_t)NHEADS * T_SEQ * HDIM * 2);
    bf16*  vp     = (bf16*)alloc((size_t)NHEADS * HDIM * T_SEQ * 2);
    float* agate  = (float*)alloc((size_t)T_SEQ * NHEADS * 4);
    float* vgate  = (float*)alloc((size_t)T_SEQ * NHEADS * 4);

    // 1. xn = rmsnorm(x)
    rmsnorm_k<<<T_SEQ, 256, 0, stream>>>(x, xn);
    // 2. weight converts
    convert_k<<<(3 * DMODEL * DMODEL) / 1024, 256, 0, stream>>>(qkvo_w, wqkv, lam, 0, (size_t)3 * DMODEL * DMODEL);
    convert_k<<<(DMODEL * DMODEL) / 1024, 256, 0, stream>>>(qkvo_w + (size_t)3 * DMODEL * DMODEL, wo, lam, 1, (size_t)DMODEL * DMODEL);
    convert_k<<<(FFN_D * DMODEL) / 1024, 256, 0, stream>>>(c_fc, wfc, nullptr, 0, (size_t)FFN_D * DMODEL);
    transpose_convert_k<<<dim3(FFN_D / 32, DMODEL / 32), 256, 0, stream>>>(c_proj, wprojT);
    // 3. qkv = xn @ wqkv^T
    gemm_bt<0><<<dim3(3 * DMODEL / 128, T_SEQ / 128), 256, 0, stream>>>(xn, wqkv, qkv, nullptr, nullptr, T_SEQ, 3 * DMODEL, DMODEL);
    // 4. gates
    gates_k<<<T_SEQ, 256, 0, stream>>>(xn, agw, vgw, agate, vgate);
    // 5. q/k rmsnorm+rope, v += gate*ve (vp transposed)
    qkvproc_k<<<dim3(T_SEQ, NHEADS), 64, 0, stream>>>(qkv, cosb, sinb, ve, vgate, qp, kp, vp);
    // 6. attention (key-shift fused into staging), attn gate fused into epilogue
    fattn_k<<<dim3(T_SEQ / 64, NHEADS), 256, 0, stream>>>(qp, kp, vp, docs, ascale, agate, keyoff, ybuf);
    // 7. out = x + y @ wo^T
    gemm_bt<1><<<dim3(DMODEL / 128, T_SEQ / 128), 256, 0, stream>>>(ybuf, wo, out, nullptr, x, T_SEQ, DMODEL, DMODEL);
    // 8. xn2 = rmsnorm(out)  (reuse xn buffer)
    rmsnorm_k<<<T_SEQ, 256, 0, stream>>>(out, xn);
    // 9. h = relu(xn2 @ wfc^T)^2 -> bf16
    gemm_bt<2><<<dim3(FFN_D / 128, T_SEQ / 128), 256, 0, stream>>>(xn, wfc, nullptr, hbuf, nullptr, T_SEQ, FFN_D, DMODEL);
    // 10. out = out + h @ wprojT^T
    gemm_bt<1><<<dim3(DMODEL / 128, T_SEQ / 128), 256, 0, stream>>>(hbuf, wprojT, out, nullptr, out, T_SEQ, DMODEL, FFN_D);
}

// Round 2
// 754.299 us; speedup vs baseline: 1.0929x; 1.0929x over previous
//
#include <hip/hip_runtime.h>
#include <hip/hip_bf16.h>

#define T_SEQ 2048
#define DMODEL 2048
#define NHEADS 16
#define HDIM 128
#define FFN_D 8192
#define RMS_EPS 1.1920929e-7f

typedef __hip_bfloat16 bf16;
using bf16x8 = __attribute__((ext_vector_type(8))) short;
using f32x4  = __attribute__((ext_vector_type(4))) float;

__device__ __forceinline__ float bf2f(bf16 v) { return __bfloat162float(v); }
__device__ __forceinline__ bf16  f2bf(float v) { return __float2bfloat16(v); }

__device__ __forceinline__ void async16(const void* g, void* l) {
    __builtin_amdgcn_global_load_lds(
        (const __attribute__((address_space(1))) void*)g,
        (__attribute__((address_space(3))) void*)l,
        16, 0, 0);
}

// ---------------- RMSNorm: fp32 row -> bf16 row ----------------
__global__ __launch_bounds__(256) void rmsnorm_k(const float* __restrict__ x,
                                                 bf16* __restrict__ out) {
    int row = blockIdx.x;
    const float* xr = x + (size_t)row * DMODEL;
    int t = threadIdx.x;
    float v[8];
    float ss = 0.f;
#pragma unroll
    for (int i = 0; i < 8; ++i) { v[i] = xr[t + i * 256]; ss += v[i] * v[i]; }
#pragma unroll
    for (int o = 32; o > 0; o >>= 1) ss += __shfl_xor(ss, o, 64);
    __shared__ float wsum[4];
    int wave = t >> 6;
    if ((t & 63) == 0) wsum[wave] = ss;
    __syncthreads();
    ss = wsum[0] + wsum[1] + wsum[2] + wsum[3];
    float sc = rsqrtf(ss * (1.0f / DMODEL) + RMS_EPS);
    bf16* orow = out + (size_t)row * DMODEL;
#pragma unroll
    for (int i = 0; i < 8; ++i) orow[t + i * 256] = f2bf(v[i] * sc);
}

// ---------------- scale+convert fp32 -> bf16 ----------------
__global__ __launch_bounds__(256) void convert_k(const float* __restrict__ in,
                                                 bf16* __restrict__ out,
                                                 const float* __restrict__ lam, int li,
                                                 size_t n) {
    float s = lam ? lam[li] : 1.0f;
    size_t i = (size_t)blockIdx.x * 1024 + (size_t)threadIdx.x * 4;
    if (i + 3 < n) {
        float4 f = *(const float4*)(in + i);
        bf16 h0 = f2bf(f.x * s), h1 = f2bf(f.y * s), h2 = f2bf(f.z * s), h3 = f2bf(f.w * s);
        short4 o;
        o.x = *(short*)&h0; o.y = *(short*)&h1; o.z = *(short*)&h2; o.w = *(short*)&h3;
        *(short4*)((short*)out + i) = o;
    }
}

// ---------------- transpose + convert: c_proj (FFN x D) -> (D x FFN) bf16 ----------------
__global__ __launch_bounds__(256) void transpose_convert_k(const float* __restrict__ in,
                                                           bf16* __restrict__ out) {
    __shared__ float tile[32][33];
    int f0 = blockIdx.x * 32;
    int d0 = blockIdx.y * 32;
    int tx = threadIdx.x & 31, ty = threadIdx.x >> 5;
#pragma unroll
    for (int i = 0; i < 32; i += 8)
        tile[ty + i][tx] = in[(size_t)(f0 + ty + i) * DMODEL + d0 + tx];
    __syncthreads();
#pragma unroll
    for (int i = 0; i < 32; i += 8)
        out[(size_t)(d0 + ty + i) * FFN_D + f0 + tx] = f2bf(tile[tx][ty + i]);
}

// ---------------- partial reduce: out = base + sum(parts[p]) ----------------
template <int NP>
__global__ __launch_bounds__(256) void reduce_k(const float* __restrict__ base,
                                                const float* __restrict__ parts,
                                                float* __restrict__ out, size_t n) {
    size_t i = ((size_t)blockIdx.x * 256 + threadIdx.x) * 4;
    if (i >= n) return;
    float4 acc = *(const float4*)(base + i);
#pragma unroll
    for (int p = 0; p < NP; ++p) {
        float4 v = *(const float4*)(parts + (size_t)p * n + i);
        acc.x += v.x; acc.y += v.y; acc.z += v.z; acc.w += v.w;
    }
    *(float4*)(out + i) = acc;
}

// ---------------- GEMM: C(MxN) = A(MxK) * B(NxK)^T, bf16 inputs, fp32 acc ----------------
// EPI: 0 = fp32 out (split-K partial: + blockIdx.z*M*N), 1 = fp32 out + addsrc, 2 = bf16 relu^2
// LDS tiles are XOR-swizzled: stored[R][c] = global[R][c ^ ((R>>1)&3)], chunk = 8 shorts.
template <int EPI>
__global__ __launch_bounds__(256) void gemm_bt(const bf16* __restrict__ A,
                                               const bf16* __restrict__ B,
                                               float* __restrict__ Cf,
                                               bf16* __restrict__ Cb,
                                               const float* __restrict__ addsrc,
                                               int M, int N, int K, int Klen) {
    __shared__ alignas(16) short lA[128 * 32];
    __shared__ alignas(16) short lB[128 * 32];
    int t = threadIdx.x;
    int wave = t >> 6, lane = t & 63;
    int m0 = blockIdx.y * 128, n0 = blockIdx.x * 128;
    int wm = (wave >> 1) * 64, wn = (wave & 1) * 64;
    int lr = lane & 15, kq = lane >> 4;

    f32x4 acc[4][4];
#pragma unroll
    for (int i = 0; i < 4; ++i)
#pragma unroll
        for (int j = 0; j < 4; ++j) acc[i][j] = (f32x4)0.0f;

    int srow = wave * 16 + (lane >> 2);
    int scol = ((lane & 3) ^ ((lane >> 3) & 3)) * 8;   // XOR-swizzled source chunk
    const bf16* gA0 = A + (size_t)(m0 + srow) * K + scol;
    const bf16* gA1 = A + (size_t)(m0 + 64 + srow) * K + scol;
    const bf16* gB0 = B + (size_t)(n0 + srow) * K + scol;
    const bf16* gB1 = B + (size_t)(n0 + 64 + srow) * K + scol;
    short* lA0 = lA + (wave * 16) * 32;
    short* lA1 = lA + (64 + wave * 16) * 32;
    short* lB0 = lB + (wave * 16) * 32;
    short* lB1 = lB + (64 + wave * 16) * 32;

    int sw = (lr >> 1) & 3;  // read-side swizzle (row low bits come only from lr)
    int kbeg = blockIdx.z * Klen;
    for (int k0 = kbeg; k0 < kbeg + Klen; k0 += 32) {
        async16(gA0 + k0, lA0);
        async16(gA1 + k0, lA1);
        async16(gB0 + k0, lB0);
        async16(gB1 + k0, lB1);
        __syncthreads();
        bf16x8 af[4], bfr[4];
#pragma unroll
        for (int mi = 0; mi < 4; ++mi)
            af[mi] = *(const bf16x8*)&lA[(wm + mi * 16 + lr) * 32 + (kq ^ sw) * 8];
#pragma unroll
        for (int ni = 0; ni < 4; ++ni)
            bfr[ni] = *(const bf16x8*)&lB[(wn + ni * 16 + lr) * 32 + (kq ^ sw) * 8];
#pragma unroll
        for (int mi = 0; mi < 4; ++mi)
#pragma unroll
            for (int ni = 0; ni < 4; ++ni)
                acc[mi][ni] = __builtin_amdgcn_mfma_f32_16x16x32_bf16(af[mi], bfr[ni], acc[mi][ni], 0, 0, 0);
        __syncthreads();
    }

    float* Cpart = (EPI == 0) ? Cf + (size_t)blockIdx.z * M * N : Cf;
#pragma unroll
    for (int mi = 0; mi < 4; ++mi)
#pragma unroll
        for (int ni = 0; ni < 4; ++ni)
#pragma unroll
            for (int r = 0; r < 4; ++r) {
                int row = m0 + wm + mi * 16 + kq * 4 + r;
                int col = n0 + wn + ni * 16 + lr;
                float v = acc[mi][ni][r];
                size_t idx = (size_t)row * N + col;
                if (EPI == 0) {
                    Cpart[idx] = v;
                } else if (EPI == 1) {
                    Cf[idx] = addsrc[idx] + v;
                } else {
                    float rv = fmaxf(v, 0.f);
                    Cb[idx] = f2bf(rv * rv);
                }
            }
}

// ---------------- attention + ve gates (sigmoid of xn . w_h) ----------------
__global__ __launch_bounds__(256) void gates_k(const bf16* __restrict__ xn,
                                               const float* __restrict__ agw,
                                               const float* __restrict__ vgw,
                                               float* __restrict__ ag,
                                               float* __restrict__ vg) {
    int trow = blockIdx.x;
    __shared__ float xr[DMODEL];
    int t = threadIdx.x;
#pragma unroll
    for (int i = 0; i < 8; ++i) xr[t + i * 256] = bf2f(xn[(size_t)trow * DMODEL + t + i * 256]);
    __syncthreads();
    int wave = t >> 6, lane = t & 63;
#pragma unroll
    for (int hh = 0; hh < 4; ++hh) {
        int h = wave * 4 + hh;
        float sa = 0.f, sv = 0.f;
        for (int d = lane; d < DMODEL; d += 64) {
            float xv = xr[d];
            sa += xv * agw[h * DMODEL + d];
            sv += xv * vgw[h * DMODEL + d];
        }
#pragma unroll
        for (int o = 32; o > 0; o >>= 1) {
            sa += __shfl_xor(sa, o, 64);
            sv += __shfl_xor(sv, o, 64);
        }
        if (lane == 0) {
            ag[trow * NHEADS + h] = 1.f / (1.f + __expf(-sa));
            vg[trow * NHEADS + h] = 1.f / (1.f + __expf(-sv));
        }
    }
}

// ---------------- qkv post-processing: per-head rmsnorm + rope; v += gate*ve ----------------
// outputs: qp (H,T,HD) bf16 ; kp (H,T,HD) bf16 (rotated, UNshifted) ; vp (H,HD,T) bf16
__global__ __launch_bounds__(64) void qkvproc_k(const float* __restrict__ qkv,
                                                const float* __restrict__ cosb,
                                                const float* __restrict__ sinb,
                                                const float* __restrict__ ve,
                                                const float* __restrict__ vg,
                                                bf16* __restrict__ qp,
                                                bf16* __restrict__ kp,
                                                bf16* __restrict__ vp) {
    int trow = blockIdx.x, h = blockIdx.y, lane = threadIdx.x;
    const float* base = qkv + (size_t)trow * (3 * DMODEL);
    float q0 = base[h * HDIM + lane], q1 = base[h * HDIM + lane + 64];
    float k0 = base[DMODEL + h * HDIM + lane], k1 = base[DMODEL + h * HDIM + lane + 64];
    float v0 = base[2 * DMODEL + h * HDIM + lane], v1 = base[2 * DMODEL + h * HDIM + lane + 64];
    float ssq = q0 * q0 + q1 * q1, ssk = k0 * k0 + k1 * k1;
#pragma unroll
    for (int o = 32; o > 0; o >>= 1) {
        ssq += __shfl_xor(ssq, o, 64);
        ssk += __shfl_xor(ssk, o, 64);
    }
    float scq = rsqrtf(ssq * (1.f / HDIM) + RMS_EPS);
    float sck = rsqrtf(ssk * (1.f / HDIM) + RMS_EPS);
    q0 *= scq; q1 *= scq; k0 *= sck; k1 *= sck;
    float c = cosb[trow * 64 + lane], s = sinb[trow * 64 + lane];
    float qo0 = q0 * c + q1 * s, qo1 = -q0 * s + q1 * c;
    float ko0 = k0 * c + k1 * s, ko1 = -k0 * s + k1 * c;
    size_t o = ((size_t)h * T_SEQ + trow) * HDIM + lane;
    qp[o] = f2bf(qo0); qp[o + 64] = f2bf(qo1);
    kp[o] = f2bf(ko0); kp[o + 64] = f2bf(ko1);
    float g = vg[trow * NHEADS + h];
    v0 += g * ve[(size_t)trow * DMODEL + h * HDIM + lane];
    v1 += g * ve[(size_t)trow * DMODEL + h * HDIM + lane + 64];
    vp[((size_t)h * HDIM + lane) * T_SEQ + trow] = f2bf(v0);
    vp[((size_t)h * HDIM + lane + 64) * T_SEQ + trow] = f2bf(v1);
}

// ---------------- flash attention (doc-masked causal), key-shift during staging ----------------
__global__ __launch_bounds__(256) void fattn_k(const bf16* __restrict__ qp,
                                               const bf16* __restrict__ kp,
                                               const bf16* __restrict__ vp,
                                               const int* __restrict__ docs,
                                               const float* __restrict__ scale_p,
                                               const float* __restrict__ ag,
                                               const int* __restrict__ keyoff,
                                               bf16* __restrict__ y) {
    int h = blockIdx.y;
    int q0 = blockIdx.x * 64;
    int t = threadIdx.x, wave = t >> 6, lane = t & 63;
    int lr = lane & 15, kq = lane >> 4;
    __shared__ alignas(16) short sQ[64 * 128];
    __shared__ alignas(16) short sK[64 * 128];
    __shared__ alignas(16) short sV[128 * 64];
    __shared__ alignas(16) short sP[4][16 * 64];

    const bf16* qh = qp + (size_t)h * T_SEQ * HDIM;
    const bf16* kh = kp + (size_t)h * T_SEQ * HDIM;
    const bf16* vh = vp + (size_t)h * HDIM * T_SEQ;
    int ko = keyoff[0];

    // stage Q (64 x 128)
    {
        int srow = wave * 4 + (lane >> 4);
        int scq = (lane & 15) * 8;
#pragma unroll
        for (int i = 0; i < 4; ++i)
            async16(qh + (size_t)(q0 + i * 16 + srow) * HDIM + scq, &sQ[(i * 16 + wave * 4) * HDIM]);
    }
    __syncthreads();
    bf16x8 qf[4];
#pragma unroll
    for (int kk = 0; kk < 4; ++kk)
        qf[kk] = *(const bf16x8*)&sQ[(wave * 16 + lr) * HDIM + kk * 32 + kq * 8];

    float scl = scale_p[0];
    int myq[4], mydoc[4];
#pragma unroll
    for (int r = 0; r < 4; ++r) {
        myq[r] = q0 + wave * 16 + kq * 4 + r;
        mydoc[r] = docs[myq[r]];
    }
    float m_i[4], l_i[4];
#pragma unroll
    for (int r = 0; r < 4; ++r) { m_i[r] = -1e30f; l_i[r] = 0.f; }
    f32x4 oacc[8];
#pragma unroll
    for (int i = 0; i < 8; ++i) oacc[i] = (f32x4)0.f;

    // doc skip: first s with docs[s] == docs[q0]
    int dq0 = docs[q0];
    int lo = 0, hi = q0;
    while (lo < hi) { int mid = (lo + hi) >> 1; if (docs[mid] < dq0) lo = mid + 1; else hi = mid; }
    int s_begin = lo & ~63;

    for (int s0 = s_begin; s0 <= q0; s0 += 64) {
        // stage K (64 x 128) with key-shift applied per 16B chunk
        {
            int rbase = wave * 4 + (lane >> 4);
            int scq = (lane & 15) * 8;
            int band = (scq >> 5) & 1;
#pragma unroll
            for (int i = 0; i < 4; ++i) {
                int g = s0 + i * 16 + rbase;
                int ts = (ko && band && g > 0) ? g - 1 : g;
                async16(kh + (size_t)ts * HDIM + scq, &sK[(i * 16 + wave * 4) * HDIM]);
            }
            // stage V^T (128 x 64)
            int vrow = wave * 8 + (lane >> 3);
            int vcq = (lane & 7) * 8;
#pragma unroll
            for (int i = 0; i < 4; ++i)
                async16(vh + (size_t)(i * 32 + vrow) * T_SEQ + s0 + vcq, &sV[(i * 32 + wave * 8) * 64]);
        }
        __syncthreads();

        // S = Q K^T
        f32x4 sc[4];
#pragma unroll
        for (int ni = 0; ni < 4; ++ni) {
            sc[ni] = (f32x4)0.f;
#pragma unroll
            for (int kk = 0; kk < 4; ++kk) {
                bf16x8 bfrag = *(const bf16x8*)&sK[(ni * 16 + lr) * HDIM + kk * 32 + kq * 8];
                sc[ni] = __builtin_amdgcn_mfma_f32_16x16x32_bf16(qf[kk], bfrag, sc[ni], 0, 0, 0);
            }
        }
        // mask + scale
        float pv[4][4];
        float mt[4];
#pragma unroll
        for (int r = 0; r < 4; ++r) mt[r] = -1e30f;
#pragma unroll
        for (int ni = 0; ni < 4; ++ni) {
            int scol = s0 + ni * 16 + lr;
            int sdoc = docs[scol];
#pragma unroll
            for (int r = 0; r < 4; ++r) {
                float v = sc[ni][r] * scl;
                if (scol > myq[r] || sdoc != mydoc[r]) v = -1e30f;
                pv[ni][r] = v;
                mt[r] = fmaxf(mt[r], v);
            }
        }
#pragma unroll
        for (int r = 0; r < 4; ++r) {
#pragma unroll
            for (int o = 1; o < 16; o <<= 1) mt[r] = fmaxf(mt[r], __shfl_xor(mt[r], o, 64));
        }
        float alpha[4], rsum[4];
#pragma unroll
        for (int r = 0; r < 4; ++r) {
            float mnew = fmaxf(m_i[r], mt[r]);
            alpha[r] = __expf(m_i[r] - mnew);
            m_i[r] = mnew;
            rsum[r] = 0.f;
        }
#pragma unroll
        for (int ni = 0; ni < 4; ++ni)
#pragma unroll
            for (int r = 0; r < 4; ++r) {
                float p = __expf(pv[ni][r] - m_i[r]);
                pv[ni][r] = p;
                rsum[r] += p;
            }
#pragma unroll
        for (int r = 0; r < 4; ++r) {
#pragma unroll
            for (int o = 1; o < 16; o <<= 1) rsum[r] += __shfl_xor(rsum[r], o, 64);
            l_i[r] = l_i[r] * alpha[r] + rsum[r];
        }
#pragma unroll
        for (int i = 0; i < 8; ++i)
#pragma unroll
            for (int r = 0; r < 4; ++r) oacc[i][r] *= alpha[r];

        // P (C-layout) -> LDS -> A-layout
#pragma unroll
        for (int ni = 0; ni < 4; ++ni)
#pragma unroll
            for (int r = 0; r < 4; ++r) {
                bf16 b = f2bf(pv[ni][r]);
                sP[wave][(kq * 4 + r) * 64 + ni * 16 + lr] = *(short*)&b;
            }
        bf16x8 pf[2];
#pragma unroll
        for (int kk = 0; kk < 2; ++kk)
            pf[kk] = *(const bf16x8*)&sP[wave][lr * 64 + kk * 32 + kq * 8];
#pragma unroll
        for (int oi = 0; oi < 8; ++oi) {
#pragma unroll
            for (int kk = 0; kk < 2; ++kk) {
                bf16x8 vfrag = *(const bf16x8*)&sV[(oi * 16 + lr) * 64 + kk * 32 + kq * 8];
                oacc[oi] = __builtin_amdgcn_mfma_f32_16x16x32_bf16(pf[kk], vfrag, oacc[oi], 0, 0, 0);
            }
        }
        __syncthreads();
    }

    // epilogue: y[t, h*128+d] = gate * O / l
#pragma unroll
    for (int r = 0; r < 4; ++r) {
        int row = myq[r];
        float g = ag[row * NHEADS + h];
        float inv = g / l_i[r];
#pragma unroll
        for (int oi = 0; oi < 8; ++oi)
            y[(size_t)row * DMODEL + h * HDIM + oi * 16 + lr] = f2bf(oacc[oi][r] * inv);
    }
}

extern "C" void kernel_launch(void* const* d_in, const int* in_sizes, int n_in,
                              void* d_out, int out_size, void* d_ws, size_t ws_size,
                              hipStream_t stream) {
    (void)in_sizes; (void)n_in; (void)out_size; (void)ws_size;
    const float* x      = (const float*)d_in[0];
    const float* ve     = (const float*)d_in[1];
    const float* qkvo_w = (const float*)d_in[2];
    const float* agw    = (const float*)d_in[3];
    const float* vgw    = (const float*)d_in[4];
    const float* c_fc   = (const float*)d_in[5];
    const float* c_proj = (const float*)d_in[6];
    const float* lam    = (const float*)d_in[7];
    const float* cosb   = (const float*)d_in[8];
    const float* sinb   = (const float*)d_in[9];
    const float* ascale = (const float*)d_in[10];
    const int*   docs   = (const int*)d_in[11];
    const int*   keyoff = (const int*)d_in[12];
    float* out = (float*)d_out;

    char* ws = (char*)d_ws;
    size_t off = 0;
    auto alloc = [&](size_t bytes) {
        char* p = ws + off;
        off += (bytes + 255) & ~(size_t)255;
        return p;
    };
    bf16*  xn     = (bf16*)alloc((size_t)T_SEQ * DMODEL * 2);
    // wqkv+wo+wfc occupy a contiguous 67.1 MB region; PROJ split-4 partials
    // (4 x 2048 x 2048 fp32 = 67.1 MB) alias it after steps 3/7/9 consume them.
    char*  wregion = alloc((size_t)3 * DMODEL * DMODEL * 2 +
                           (size_t)DMODEL * DMODEL * 2 +
                           (size_t)FFN_D * DMODEL * 2);
    bf16*  wqkv   = (bf16*)wregion;
    bf16*  wo     = (bf16*)(wregion + (size_t)3 * DMODEL * DMODEL * 2);
    bf16*  wfc    = (bf16*)(wregion + (size_t)4 * DMODEL * DMODEL * 2);
    float* projpart = (float*)wregion;                        // 4 partials, step 10
    bf16*  wprojT = (bf16*)alloc((size_t)DMODEL * FFN_D * 2);
    char*  qkvreg = alloc((size_t)T_SEQ * 3 * DMODEL * 4);    // 50.3 MB region
    float* qkv    = (float*)qkvreg;                           // steps 3-5 (fp32)
    float* opart  = (float*)qkvreg;                           // 2 partials (33.5MB), step 7
    bf16*  hbuf   = (bf16*)qkvreg;                            // steps 9-10 (33.5 MB)
    bf16*  ybuf   = (bf16*)(qkvreg + (size_t)T_SEQ * FFN_D * 2); // steps 6-7 (8.4 MB)
    bf16*  qp     = (bf16*)alloc((size_t)NHEADS * T_SEQ * HDIM * 2);
    bf16*  kp     = (bf16*)alloc((size_t)NHEADS * T_SEQ * HDIM * 2);
    bf16*  vp     = (bf16*)alloc((size_t)NHEADS * HDIM * T_SEQ * 2);
    float* agate  = (float*)alloc((size_t)T_SEQ * NHEADS * 4);
    float* vgate  = (float*)alloc((size_t)T_SEQ * NHEADS * 4);

    const size_t NN = (size_t)T_SEQ * DMODEL; // 4.19M elems

    // 1. xn = rmsnorm(x)
    rmsnorm_k<<<T_SEQ, 256, 0, stream>>>(x, xn);
    // 2. weight converts
    convert_k<<<(3 * DMODEL * DMODEL) / 1024, 256, 0, stream>>>(qkvo_w, wqkv, lam, 0, (size_t)3 * DMODEL * DMODEL);
    convert_k<<<(DMODEL * DMODEL) / 1024, 256, 0, stream>>>(qkvo_w + (size_t)3 * DMODEL * DMODEL, wo, lam, 1, (size_t)DMODEL * DMODEL);
    convert_k<<<(FFN_D * DMODEL) / 1024, 256, 0, stream>>>(c_fc, wfc, nullptr, 0, (size_t)FFN_D * DMODEL);
    transpose_convert_k<<<dim3(FFN_D / 32, DMODEL / 32), 256, 0, stream>>>(c_proj, wprojT);
    // 3. qkv = xn @ wqkv^T
    gemm_bt<0><<<dim3(3 * DMODEL / 128, T_SEQ / 128, 1), 256, 0, stream>>>(xn, wqkv, qkv, nullptr, nullptr, T_SEQ, 3 * DMODEL, DMODEL, DMODEL);
    // 4. gates
    gates_k<<<T_SEQ, 256, 0, stream>>>(xn, agw, vgw, agate, vgate);
    // 5. q/k rmsnorm+rope, v += gate*ve (vp transposed)
    qkvproc_k<<<dim3(T_SEQ, NHEADS), 64, 0, stream>>>(qkv, cosb, sinb, ve, vgate, qp, kp, vp);
    // 6. attention (key-shift fused into staging), attn gate fused into epilogue
    fattn_k<<<dim3(T_SEQ / 64, NHEADS), 256, 0, stream>>>(qp, kp, vp, docs, ascale, agate, keyoff, ybuf);
    // 7. attn proj, split-K=2 -> partials; then out = x + p0 + p1
    gemm_bt<0><<<dim3(DMODEL / 128, T_SEQ / 128, 2), 256, 0, stream>>>(ybuf, wo, opart, nullptr, nullptr, T_SEQ, DMODEL, DMODEL, DMODEL / 2);
    reduce_k<2><<<NN / 1024, 256, 0, stream>>>(x, opart, out, NN);
    // 8. xn2 = rmsnorm(out)  (reuse xn buffer)
    rmsnorm_k<<<T_SEQ, 256, 0, stream>>>(out, xn);
    // 9. h = relu(xn2 @ wfc^T)^2 -> bf16
    gemm_bt<2><<<dim3(FFN_D / 128, T_SEQ / 128, 1), 256, 0, stream>>>(xn, wfc, nullptr, hbuf, nullptr, T_SEQ, FFN_D, DMODEL, DMODEL);
    // 10. mlp proj, split-K=4 -> partials; then out += p0..p3
    gemm_bt<0><<<dim3(DMODEL / 128, T_SEQ / 128, 4), 256, 0, stream>>>(hbuf, wprojT, projpart, nullptr, nullptr, T_SEQ, DMODEL, FFN_D, FFN_D / 4);
    reduce_k<4><<<NN / 1024, 256, 0, stream>>>(out, projpart, out, NN);
}

// Round 3
// 688.304 us; speedup vs baseline: 1.1977x; 1.0959x over previous
//
#include <hip/hip_runtime.h>
#include <hip/hip_bf16.h>

#define T_SEQ 2048
#define DMODEL 2048
#define NHEADS 16
#define HDIM 128
#define FFN_D 8192
#define RMS_EPS 1.1920929e-7f

typedef __hip_bfloat16 bf16;
using bf16x8 = __attribute__((ext_vector_type(8))) short;
using f32x4  = __attribute__((ext_vector_type(4))) float;

__device__ __forceinline__ float bf2f(bf16 v) { return __bfloat162float(v); }
__device__ __forceinline__ bf16  f2bf(float v) { return __float2bfloat16(v); }

__device__ __forceinline__ void async16(const void* g, void* l) {
    __builtin_amdgcn_global_load_lds(
        (const __attribute__((address_space(1))) void*)g,
        (__attribute__((address_space(3))) void*)l,
        16, 0, 0);
}

// ---------------- RMSNorm: fp32 row -> bf16 row ----------------
__global__ __launch_bounds__(256) void rmsnorm_k(const float* __restrict__ x,
                                                 bf16* __restrict__ out) {
    int row = blockIdx.x;
    const float* xr = x + (size_t)row * DMODEL;
    int t = threadIdx.x;
    float v[8];
    float ss = 0.f;
#pragma unroll
    for (int i = 0; i < 8; ++i) { v[i] = xr[t + i * 256]; ss += v[i] * v[i]; }
#pragma unroll
    for (int o = 32; o > 0; o >>= 1) ss += __shfl_xor(ss, o, 64);
    __shared__ float wsum[4];
    int wave = t >> 6;
    if ((t & 63) == 0) wsum[wave] = ss;
    __syncthreads();
    ss = wsum[0] + wsum[1] + wsum[2] + wsum[3];
    float sc = rsqrtf(ss * (1.0f / DMODEL) + RMS_EPS);
    bf16* orow = out + (size_t)row * DMODEL;
#pragma unroll
    for (int i = 0; i < 8; ++i) orow[t + i * 256] = f2bf(v[i] * sc);
}

// ---------------- scale+convert fp32 -> bf16 ----------------
__global__ __launch_bounds__(256) void convert_k(const float* __restrict__ in,
                                                 bf16* __restrict__ out,
                                                 const float* __restrict__ lam, int li,
                                                 size_t n) {
    float s = lam ? lam[li] : 1.0f;
    size_t i = (size_t)blockIdx.x * 1024 + (size_t)threadIdx.x * 4;
    if (i + 3 < n) {
        float4 f = *(const float4*)(in + i);
        bf16 h0 = f2bf(f.x * s), h1 = f2bf(f.y * s), h2 = f2bf(f.z * s), h3 = f2bf(f.w * s);
        short4 o;
        o.x = *(short*)&h0; o.y = *(short*)&h1; o.z = *(short*)&h2; o.w = *(short*)&h3;
        *(short4*)((short*)out + i) = o;
    }
}

// ---------------- transpose + convert: c_proj (FFN x D) -> (D x FFN) bf16 ----------------
__global__ __launch_bounds__(256) void transpose_convert_k(const float* __restrict__ in,
                                                           bf16* __restrict__ out) {
    __shared__ float tile[32][33];
    int f0 = blockIdx.x * 32;
    int d0 = blockIdx.y * 32;
    int tx = threadIdx.x & 31, ty = threadIdx.x >> 5;
#pragma unroll
    for (int i = 0; i < 32; i += 8)
        tile[ty + i][tx] = in[(size_t)(f0 + ty + i) * DMODEL + d0 + tx];
    __syncthreads();
#pragma unroll
    for (int i = 0; i < 32; i += 8)
        out[(size_t)(d0 + ty + i) * FFN_D + f0 + tx] = f2bf(tile[tx][ty + i]);
}

// ---------------- partial reduce: out = base + sum(parts[p]) ----------------
template <int NP>
__global__ __launch_bounds__(256) void reduce_k(const float* __restrict__ base,
                                                const float* __restrict__ parts,
                                                float* __restrict__ out, size_t n) {
    size_t i = ((size_t)blockIdx.x * 256 + threadIdx.x) * 4;
    if (i >= n) return;
    float4 acc = *(const float4*)(base + i);
#pragma unroll
    for (int p = 0; p < NP; ++p) {
        float4 v = *(const float4*)(parts + (size_t)p * n + i);
        acc.x += v.x; acc.y += v.y; acc.z += v.z; acc.w += v.w;
    }
    *(float4*)(out + i) = acc;
}

// ---------------- fused: out = x + p0 + p1 ; xn = rmsnorm(out) ----------------
__global__ __launch_bounds__(256) void reduce2_rms_k(const float* __restrict__ x,
                                                     const float* __restrict__ parts,
                                                     float* __restrict__ out,
                                                     bf16* __restrict__ xn) {
    int row = blockIdx.x;
    int t = threadIdx.x;
    const size_t n = (size_t)T_SEQ * DMODEL;
    const float* xr = x + (size_t)row * DMODEL;
    const float* p0 = parts + (size_t)row * DMODEL;
    const float* p1 = parts + n + (size_t)row * DMODEL;
    float v[8];
    float ss = 0.f;
#pragma unroll
    for (int i = 0; i < 8; ++i) {
        int c = t + i * 256;
        v[i] = xr[c] + p0[c] + p1[c];
        ss += v[i] * v[i];
    }
#pragma unroll
    for (int o = 32; o > 0; o >>= 1) ss += __shfl_xor(ss, o, 64);
    __shared__ float wsum[4];
    int wave = t >> 6;
    if ((t & 63) == 0) wsum[wave] = ss;
    __syncthreads();
    ss = wsum[0] + wsum[1] + wsum[2] + wsum[3];
    float sc = rsqrtf(ss * (1.0f / DMODEL) + RMS_EPS);
    float* orow = out + (size_t)row * DMODEL;
    bf16* nrow = xn + (size_t)row * DMODEL;
#pragma unroll
    for (int i = 0; i < 8; ++i) {
        int c = t + i * 256;
        orow[c] = v[i];
        nrow[c] = f2bf(v[i] * sc);
    }
}

// ---------------- GEMM: C(MxN) = A(MxK) * B(NxK)^T, bf16 in, fp32 acc, BK=64 ----------------
// EPI: 0 = fp32 split-K partial (offset blockIdx.z*M*N), 2 = bf16 relu^2, 3 = bf16 plain
// LDS XOR-swizzle: stored[r][c] = global[r][c ^ (r&7)], chunk = 8 shorts (16B).
template <int EPI>
__global__ __launch_bounds__(256) void gemm_bt(const bf16* __restrict__ A,
                                               const bf16* __restrict__ B,
                                               float* __restrict__ Cf,
                                               bf16* __restrict__ Cb,
                                               int M, int N, int K, int Klen) {
    __shared__ alignas(16) short lA[128 * 64];
    __shared__ alignas(16) short lB[128 * 64];
    int t = threadIdx.x;
    int wave = t >> 6, lane = t & 63;
    int m0 = blockIdx.y * 128, n0 = blockIdx.x * 128;
    int wm = (wave >> 1) * 64, wn = (wave & 1) * 64;
    int lr = lane & 15, kq = lane >> 4;

    f32x4 acc[4][4];
#pragma unroll
    for (int i = 0; i < 4; ++i)
#pragma unroll
        for (int j = 0; j < 4; ++j) acc[i][j] = (f32x4)0.0f;

    // staging: 4 issues per tile; issue i covers rows i*32 + wave*8 .. +7
    int rsub = lane >> 3;                       // row within 8-row group
    int scol = ((lane & 7) ^ rsub) * 8;         // XOR-swizzled source chunk
    const bf16* gA = A + (size_t)(m0 + wave * 8 + rsub) * K + scol;
    const bf16* gB = B + (size_t)(n0 + wave * 8 + rsub) * K + scol;
    short* dA = lA + (wave * 8) * 64;
    short* dB = lB + (wave * 8) * 64;
    size_t rowstep = (size_t)32 * K;

    int kbeg = blockIdx.z * Klen;
    for (int k0 = kbeg; k0 < kbeg + Klen; k0 += 64) {
#pragma unroll
        for (int i = 0; i < 4; ++i) async16(gA + i * rowstep + k0, dA + i * 2048);
#pragma unroll
        for (int i = 0; i < 4; ++i) async16(gB + i * rowstep + k0, dB + i * 2048);
        __syncthreads();
        int swz = lr & 7;
#pragma unroll
        for (int ks = 0; ks < 2; ++ks) {
            bf16x8 af[4], bfr[4];
#pragma unroll
            for (int mi = 0; mi < 4; ++mi)
                af[mi] = *(const bf16x8*)&lA[(wm + mi * 16 + lr) * 64 + ((ks * 4 + kq) ^ swz) * 8];
#pragma unroll
            for (int ni = 0; ni < 4; ++ni)
                bfr[ni] = *(const bf16x8*)&lB[(wn + ni * 16 + lr) * 64 + ((ks * 4 + kq) ^ swz) * 8];
#pragma unroll
            for (int mi = 0; mi < 4; ++mi)
#pragma unroll
                for (int ni = 0; ni < 4; ++ni)
                    acc[mi][ni] = __builtin_amdgcn_mfma_f32_16x16x32_bf16(af[mi], bfr[ni], acc[mi][ni], 0, 0, 0);
        }
        __syncthreads();
    }

    float* Cpart = (EPI == 0) ? Cf + (size_t)blockIdx.z * M * N : Cf;
#pragma unroll
    for (int mi = 0; mi < 4; ++mi)
#pragma unroll
        for (int ni = 0; ni < 4; ++ni)
#pragma unroll
            for (int r = 0; r < 4; ++r) {
                int row = m0 + wm + mi * 16 + kq * 4 + r;
                int col = n0 + wn + ni * 16 + lr;
                float v = acc[mi][ni][r];
                size_t idx = (size_t)row * N + col;
                if (EPI == 0) {
                    Cpart[idx] = v;
                } else if (EPI == 2) {
                    float rv = fmaxf(v, 0.f);
                    Cb[idx] = f2bf(rv * rv);
                } else {
                    Cb[idx] = f2bf(v);
                }
            }
}

// ---------------- attention + ve gates (sigmoid of xn . w_h) ----------------
__global__ __launch_bounds__(256) void gates_k(const bf16* __restrict__ xn,
                                               const float* __restrict__ agw,
                                               const float* __restrict__ vgw,
                                               float* __restrict__ ag,
                                               float* __restrict__ vg) {
    int trow = blockIdx.x;
    __shared__ float xr[DMODEL];
    int t = threadIdx.x;
#pragma unroll
    for (int i = 0; i < 8; ++i) xr[t + i * 256] = bf2f(xn[(size_t)trow * DMODEL + t + i * 256]);
    __syncthreads();
    int wave = t >> 6, lane = t & 63;
#pragma unroll
    for (int hh = 0; hh < 4; ++hh) {
        int h = wave * 4 + hh;
        float sa = 0.f, sv = 0.f;
        for (int d = lane; d < DMODEL; d += 64) {
            float xv = xr[d];
            sa += xv * agw[h * DMODEL + d];
            sv += xv * vgw[h * DMODEL + d];
        }
#pragma unroll
        for (int o = 32; o > 0; o >>= 1) {
            sa += __shfl_xor(sa, o, 64);
            sv += __shfl_xor(sv, o, 64);
        }
        if (lane == 0) {
            ag[trow * NHEADS + h] = 1.f / (1.f + __expf(-sa));
            vg[trow * NHEADS + h] = 1.f / (1.f + __expf(-sv));
        }
    }
}

// ---------------- qkv post-processing (reads bf16 qkv): rmsnorm+rope; v += gate*ve ----------------
// wave w of 4 handles heads w*4..w*4+3.  outputs: qp/kp (H,T,HD), vp (H,HD,T)
__global__ __launch_bounds__(256) void qkvproc_k(const bf16* __restrict__ qkv,
                                                 const float* __restrict__ cosb,
                                                 const float* __restrict__ sinb,
                                                 const float* __restrict__ ve,
                                                 const float* __restrict__ vg,
                                                 bf16* __restrict__ qp,
                                                 bf16* __restrict__ kp,
                                                 bf16* __restrict__ vp) {
    int trow = blockIdx.x;
    int wave = threadIdx.x >> 6, lane = threadIdx.x & 63;
    const bf16* base = qkv + (size_t)trow * (3 * DMODEL);
    float c = cosb[trow * 64 + lane], s = sinb[trow * 64 + lane];
#pragma unroll
    for (int hh = 0; hh < 4; ++hh) {
        int h = wave * 4 + hh;
        float q0 = bf2f(base[h * HDIM + lane]), q1 = bf2f(base[h * HDIM + lane + 64]);
        float k0 = bf2f(base[DMODEL + h * HDIM + lane]), k1 = bf2f(base[DMODEL + h * HDIM + lane + 64]);
        float v0 = bf2f(base[2 * DMODEL + h * HDIM + lane]), v1 = bf2f(base[2 * DMODEL + h * HDIM + lane + 64]);
        float ssq = q0 * q0 + q1 * q1, ssk = k0 * k0 + k1 * k1;
#pragma unroll
        for (int o = 32; o > 0; o >>= 1) {
            ssq += __shfl_xor(ssq, o, 64);
            ssk += __shfl_xor(ssk, o, 64);
        }
        float scq = rsqrtf(ssq * (1.f / HDIM) + RMS_EPS);
        float sck = rsqrtf(ssk * (1.f / HDIM) + RMS_EPS);
        q0 *= scq; q1 *= scq; k0 *= sck; k1 *= sck;
        float qo0 = q0 * c + q1 * s, qo1 = -q0 * s + q1 * c;
        float ko0 = k0 * c + k1 * s, ko1 = -k0 * s + k1 * c;
        size_t o = ((size_t)h * T_SEQ + trow) * HDIM + lane;
        qp[o] = f2bf(qo0); qp[o + 64] = f2bf(qo1);
        kp[o] = f2bf(ko0); kp[o + 64] = f2bf(ko1);
        float g = vg[trow * NHEADS + h];
        v0 += g * ve[(size_t)trow * DMODEL + h * HDIM + lane];
        v1 += g * ve[(size_t)trow * DMODEL + h * HDIM + lane + 64];
        vp[((size_t)h * HDIM + lane) * T_SEQ + trow] = f2bf(v0);
        vp[((size_t)h * HDIM + lane + 64) * T_SEQ + trow] = f2bf(v1);
    }
}

// ---------------- flash attention (doc-masked causal), key-shift during staging ----------------
__global__ __launch_bounds__(256) void fattn_k(const bf16* __restrict__ qp,
                                               const bf16* __restrict__ kp,
                                               const bf16* __restrict__ vp,
                                               const int* __restrict__ docs,
                                               const float* __restrict__ scale_p,
                                               const float* __restrict__ ag,
                                               const int* __restrict__ keyoff,
                                               bf16* __restrict__ y) {
    int h = blockIdx.y;
    int q0 = blockIdx.x * 64;
    int t = threadIdx.x, wave = t >> 6, lane = t & 63;
    int lr = lane & 15, kq = lane >> 4;
    __shared__ alignas(16) short sQ[64 * 128];
    __shared__ alignas(16) short sK[64 * 128];
    __shared__ alignas(16) short sV[128 * 64];
    __shared__ alignas(16) short sP[4][16 * 64];

    const bf16* qh = qp + (size_t)h * T_SEQ * HDIM;
    const bf16* kh = kp + (size_t)h * T_SEQ * HDIM;
    const bf16* vh = vp + (size_t)h * HDIM * T_SEQ;
    int ko = keyoff[0];

    {
        int srow = wave * 4 + (lane >> 4);
        int scq = (lane & 15) * 8;
#pragma unroll
        for (int i = 0; i < 4; ++i)
            async16(qh + (size_t)(q0 + i * 16 + srow) * HDIM + scq, &sQ[(i * 16 + wave * 4) * HDIM]);
    }
    __syncthreads();
    bf16x8 qf[4];
#pragma unroll
    for (int kk = 0; kk < 4; ++kk)
        qf[kk] = *(const bf16x8*)&sQ[(wave * 16 + lr) * HDIM + kk * 32 + kq * 8];

    float scl = scale_p[0];
    int myq[4], mydoc[4];
#pragma unroll
    for (int r = 0; r < 4; ++r) {
        myq[r] = q0 + wave * 16 + kq * 4 + r;
        mydoc[r] = docs[myq[r]];
    }
    float m_i[4], l_i[4];
#pragma unroll
    for (int r = 0; r < 4; ++r) { m_i[r] = -1e30f; l_i[r] = 0.f; }
    f32x4 oacc[8];
#pragma unroll
    for (int i = 0; i < 8; ++i) oacc[i] = (f32x4)0.f;

    int dq0 = docs[q0];
    int lo = 0, hi = q0;
    while (lo < hi) { int mid = (lo + hi) >> 1; if (docs[mid] < dq0) lo = mid + 1; else hi = mid; }
    int s_begin = lo & ~63;

    for (int s0 = s_begin; s0 <= q0; s0 += 64) {
        {
            int rbase = wave * 4 + (lane >> 4);
            int scq = (lane & 15) * 8;
            int band = (scq >> 5) & 1;
#pragma unroll
            for (int i = 0; i < 4; ++i) {
                int g = s0 + i * 16 + rbase;
                int ts = (ko && band && g > 0) ? g - 1 : g;
                async16(kh + (size_t)ts * HDIM + scq, &sK[(i * 16 + wave * 4) * HDIM]);
            }
            int vrow = wave * 8 + (lane >> 3);
            int vcq = (lane & 7) * 8;
#pragma unroll
            for (int i = 0; i < 4; ++i)
                async16(vh + (size_t)(i * 32 + vrow) * T_SEQ + s0 + vcq, &sV[(i * 32 + wave * 8) * 64]);
        }
        __syncthreads();

        f32x4 sc[4];
#pragma unroll
        for (int ni = 0; ni < 4; ++ni) {
            sc[ni] = (f32x4)0.f;
#pragma unroll
            for (int kk = 0; kk < 4; ++kk) {
                bf16x8 bfrag = *(const bf16x8*)&sK[(ni * 16 + lr) * HDIM + kk * 32 + kq * 8];
                sc[ni] = __builtin_amdgcn_mfma_f32_16x16x32_bf16(qf[kk], bfrag, sc[ni], 0, 0, 0);
            }
        }
        float pv[4][4];
        float mt[4];
#pragma unroll
        for (int r = 0; r < 4; ++r) mt[r] = -1e30f;
#pragma unroll
        for (int ni = 0; ni < 4; ++ni) {
            int scol = s0 + ni * 16 + lr;
            int sdoc = docs[scol];
#pragma unroll
            for (int r = 0; r < 4; ++r) {
                float v = sc[ni][r] * scl;
                if (scol > myq[r] || sdoc != mydoc[r]) v = -1e30f;
                pv[ni][r] = v;
                mt[r] = fmaxf(mt[r], v);
            }
        }
#pragma unroll
        for (int r = 0; r < 4; ++r) {
#pragma unroll
            for (int o = 1; o < 16; o <<= 1) mt[r] = fmaxf(mt[r], __shfl_xor(mt[r], o, 64));
        }
        float alpha[4], rsum[4];
#pragma unroll
        for (int r = 0; r < 4; ++r) {
            float mnew = fmaxf(m_i[r], mt[r]);
            alpha[r] = __expf(m_i[r] - mnew);
            m_i[r] = mnew;
            rsum[r] = 0.f;
        }
#pragma unroll
        for (int ni = 0; ni < 4; ++ni)
#pragma unroll
            for (int r = 0; r < 4; ++r) {
                float p = __expf(pv[ni][r] - m_i[r]);
                pv[ni][r] = p;
                rsum[r] += p;
            }
#pragma unroll
        for (int r = 0; r < 4; ++r) {
#pragma unroll
            for (int o = 1; o < 16; o <<= 1) rsum[r] += __shfl_xor(rsum[r], o, 64);
            l_i[r] = l_i[r] * alpha[r] + rsum[r];
        }
#pragma unroll
        for (int i = 0; i < 8; ++i)
#pragma unroll
            for (int r = 0; r < 4; ++r) oacc[i][r] *= alpha[r];

#pragma unroll
        for (int ni = 0; ni < 4; ++ni)
#pragma unroll
            for (int r = 0; r < 4; ++r) {
                bf16 b = f2bf(pv[ni][r]);
                sP[wave][(kq * 4 + r) * 64 + ni * 16 + lr] = *(short*)&b;
            }
        bf16x8 pf[2];
#pragma unroll
        for (int kk = 0; kk < 2; ++kk)
            pf[kk] = *(const bf16x8*)&sP[wave][lr * 64 + kk * 32 + kq * 8];
#pragma unroll
        for (int oi = 0; oi < 8; ++oi) {
#pragma unroll
            for (int kk = 0; kk < 2; ++kk) {
                bf16x8 vfrag = *(const bf16x8*)&sV[(oi * 16 + lr) * 64 + kk * 32 + kq * 8];
                oacc[oi] = __builtin_amdgcn_mfma_f32_16x16x32_bf16(pf[kk], vfrag, oacc[oi], 0, 0, 0);
            }
        }
        __syncthreads();
    }

#pragma unroll
    for (int r = 0; r < 4; ++r) {
        int row = myq[r];
        float g = ag[row * NHEADS + h];
        float inv = g / l_i[r];
#pragma unroll
        for (int oi = 0; oi < 8; ++oi)
            y[(size_t)row * DMODEL + h * HDIM + oi * 16 + lr] = f2bf(oacc[oi][r] * inv);
    }
}

extern "C" void kernel_launch(void* const* d_in, const int* in_sizes, int n_in,
                              void* d_out, int out_size, void* d_ws, size_t ws_size,
                              hipStream_t stream) {
    (void)in_sizes; (void)n_in; (void)out_size; (void)ws_size;
    const float* x      = (const float*)d_in[0];
    const float* ve     = (const float*)d_in[1];
    const float* qkvo_w = (const float*)d_in[2];
    const float* agw    = (const float*)d_in[3];
    const float* vgw    = (const float*)d_in[4];
    const float* c_fc   = (const float*)d_in[5];
    const float* c_proj = (const float*)d_in[6];
    const float* lam    = (const float*)d_in[7];
    const float* cosb   = (const float*)d_in[8];
    const float* sinb   = (const float*)d_in[9];
    const float* ascale = (const float*)d_in[10];
    const int*   docs   = (const int*)d_in[11];
    const int*   keyoff = (const int*)d_in[12];
    float* out = (float*)d_out;

    char* ws = (char*)d_ws;
    size_t off = 0;
    auto alloc = [&](size_t bytes) {
        char* p = ws + off;
        off += (bytes + 255) & ~(size_t)255;
        return p;
    };
    bf16*  xn     = (bf16*)alloc((size_t)T_SEQ * DMODEL * 2);
    // wqkv+wo+wfc region (67.1 MB); PROJ split-4 partials alias it in step 10.
    char*  wregion = alloc((size_t)3 * DMODEL * DMODEL * 2 +
                           (size_t)DMODEL * DMODEL * 2 +
                           (size_t)FFN_D * DMODEL * 2);
    bf16*  wqkv   = (bf16*)wregion;
    bf16*  wo     = (bf16*)(wregion + (size_t)3 * DMODEL * DMODEL * 2);
    bf16*  wfc    = (bf16*)(wregion + (size_t)4 * DMODEL * DMODEL * 2);
    float* projpart = (float*)wregion;
    bf16*  wprojT = (bf16*)alloc((size_t)DMODEL * FFN_D * 2);
    char*  qkvreg = alloc((size_t)T_SEQ * 3 * DMODEL * 4);    // 50.3 MB region
    bf16*  qkvb   = (bf16*)qkvreg;                            // steps 3-5 (25.2 MB)
    float* opart  = (float*)qkvreg;                           // 2 partials (33.5MB), step 7
    bf16*  hbuf   = (bf16*)qkvreg;                            // steps 9-10 (33.5 MB)
    bf16*  ybuf   = (bf16*)(qkvreg + (size_t)T_SEQ * FFN_D * 2); // steps 6-7 (8.4 MB)
    bf16*  qp     = (bf16*)alloc((size_t)NHEADS * T_SEQ * HDIM * 2);
    bf16*  kp     = (bf16*)alloc((size_t)NHEADS * T_SEQ * HDIM * 2);
    bf16*  vp     = (bf16*)alloc((size_t)NHEADS * HDIM * T_SEQ * 2);
    float* agate  = (float*)alloc((size_t)T_SEQ * NHEADS * 4);
    float* vgate  = (float*)alloc((size_t)T_SEQ * NHEADS * 4);

    const size_t NN = (size_t)T_SEQ * DMODEL;

    // 1. xn = rmsnorm(x)
    rmsnorm_k<<<T_SEQ, 256, 0, stream>>>(x, xn);
    // 2. weight converts
    convert_k<<<(3 * DMODEL * DMODEL) / 1024, 256, 0, stream>>>(qkvo_w, wqkv, lam, 0, (size_t)3 * DMODEL * DMODEL);
    convert_k<<<(DMODEL * DMODEL) / 1024, 256, 0, stream>>>(qkvo_w + (size_t)3 * DMODEL * DMODEL, wo, lam, 1, (size_t)DMODEL * DMODEL);
    convert_k<<<(FFN_D * DMODEL) / 1024, 256, 0, stream>>>(c_fc, wfc, nullptr, 0, (size_t)FFN_D * DMODEL);
    transpose_convert_k<<<dim3(FFN_D / 32, DMODEL / 32), 256, 0, stream>>>(c_proj, wprojT);
    // 3. qkv = xn @ wqkv^T  (bf16 out)
    gemm_bt<3><<<dim3(3 * DMODEL / 128, T_SEQ / 128, 1), 256, 0, stream>>>(xn, wqkv, nullptr, qkvb, T_SEQ, 3 * DMODEL, DMODEL, DMODEL);
    // 4. gates
    gates_k<<<T_SEQ, 256, 0, stream>>>(xn, agw, vgw, agate, vgate);
    // 5. q/k rmsnorm+rope, v += gate*ve
    qkvproc_k<<<T_SEQ, 256, 0, stream>>>(qkvb, cosb, sinb, ve, vgate, qp, kp, vp);
    // 6. attention
    fattn_k<<<dim3(T_SEQ / 64, NHEADS), 256, 0, stream>>>(qp, kp, vp, docs, ascale, agate, keyoff, ybuf);
    // 7. attn proj, split-K=2 -> partials
    gemm_bt<0><<<dim3(DMODEL / 128, T_SEQ / 128, 2), 256, 0, stream>>>(ybuf, wo, opart, nullptr, T_SEQ, DMODEL, DMODEL, DMODEL / 2);
    // 8. out = x + p0 + p1 ; xn = rmsnorm(out)
    reduce2_rms_k<<<T_SEQ, 256, 0, stream>>>(x, opart, out, xn);
    // 9. h = relu(xn2 @ wfc^T)^2 -> bf16
    gemm_bt<2><<<dim3(FFN_D / 128, T_SEQ / 128, 1), 256, 0, stream>>>(xn, wfc, nullptr, hbuf, T_SEQ, FFN_D, DMODEL, DMODEL);
    // 10. mlp proj, split-K=4 -> partials; then out += p0..p3
    gemm_bt<0><<<dim3(DMODEL / 128, T_SEQ / 128, 4), 256, 0, stream>>>(hbuf, wprojT, projpart, nullptr, T_SEQ, DMODEL, FFN_D, FFN_D / 4);
    reduce_k<4><<<NN / 1024, 256, 0, stream>>>(out, projpart, out, NN);
}

// Round 4
// 642.187 us; speedup vs baseline: 1.2837x; 1.0718x over previous
//
#include <hip/hip_runtime.h>
#include <hip/hip_bf16.h>

#define T_SEQ 2048
#define DMODEL 2048
#define NHEADS 16
#define HDIM 128
#define FFN_D 8192
#define RMS_EPS 1.1920929e-7f

typedef __hip_bfloat16 bf16;
using bf16x8 = __attribute__((ext_vector_type(8))) short;
using f32x4  = __attribute__((ext_vector_type(4))) float;
using f32x16 = __attribute__((ext_vector_type(16))) float;

__device__ __forceinline__ float bf2f(bf16 v) { return __bfloat162float(v); }
__device__ __forceinline__ bf16  f2bf(float v) { return __float2bfloat16(v); }

__device__ __forceinline__ void async16(const void* g, void* l) {
    __builtin_amdgcn_global_load_lds(
        (const __attribute__((address_space(1))) void*)g,
        (__attribute__((address_space(3))) void*)l,
        16, 0, 0);
}

// ---------------- RMSNorm: fp32 row -> bf16 row ----------------
__global__ __launch_bounds__(256) void rmsnorm_k(const float* __restrict__ x,
                                                 bf16* __restrict__ out) {
    int row = blockIdx.x;
    const float* xr = x + (size_t)row * DMODEL;
    int t = threadIdx.x;
    float v[8];
    float ss = 0.f;
#pragma unroll
    for (int i = 0; i < 8; ++i) { v[i] = xr[t + i * 256]; ss += v[i] * v[i]; }
#pragma unroll
    for (int o = 32; o > 0; o >>= 1) ss += __shfl_xor(ss, o, 64);
    __shared__ float wsum[4];
    int wave = t >> 6;
    if ((t & 63) == 0) wsum[wave] = ss;
    __syncthreads();
    ss = wsum[0] + wsum[1] + wsum[2] + wsum[3];
    float sc = rsqrtf(ss * (1.0f / DMODEL) + RMS_EPS);
    bf16* orow = out + (size_t)row * DMODEL;
#pragma unroll
    for (int i = 0; i < 8; ++i) orow[t + i * 256] = f2bf(v[i] * sc);
}

// ---------------- scale+convert fp32 -> bf16 ----------------
__global__ __launch_bounds__(256) void convert_k(const float* __restrict__ in,
                                                 bf16* __restrict__ out,
                                                 const float* __restrict__ lam, int li,
                                                 size_t n) {
    float s = lam ? lam[li] : 1.0f;
    size_t i = (size_t)blockIdx.x * 1024 + (size_t)threadIdx.x * 4;
    if (i + 3 < n) {
        float4 f = *(const float4*)(in + i);
        bf16 h0 = f2bf(f.x * s), h1 = f2bf(f.y * s), h2 = f2bf(f.z * s), h3 = f2bf(f.w * s);
        short4 o;
        o.x = *(short*)&h0; o.y = *(short*)&h1; o.z = *(short*)&h2; o.w = *(short*)&h3;
        *(short4*)((short*)out + i) = o;
    }
}

// ---------------- transpose + convert: c_proj (FFN x D) -> (D x FFN) bf16 ----------------
__global__ __launch_bounds__(256) void transpose_convert_k(const float* __restrict__ in,
                                                           bf16* __restrict__ out) {
    __shared__ float tile[32][33];
    int f0 = blockIdx.x * 32;
    int d0 = blockIdx.y * 32;
    int tx = threadIdx.x & 31, ty = threadIdx.x >> 5;
#pragma unroll
    for (int i = 0; i < 32; i += 8)
        tile[ty + i][tx] = in[(size_t)(f0 + ty + i) * DMODEL + d0 + tx];
    __syncthreads();
#pragma unroll
    for (int i = 0; i < 32; i += 8)
        out[(size_t)(d0 + ty + i) * FFN_D + f0 + tx] = f2bf(tile[tx][ty + i]);
}

// ---------------- bf16 transpose: in (T x D) -> out (D x T), 64x64 tiles ----------------
__global__ __launch_bounds__(256) void transpose16_k(const bf16* __restrict__ in,
                                                     bf16* __restrict__ out,
                                                     int R, int C) {  // in is R x C
    __shared__ short lt[64][68];
    int r0 = blockIdx.y * 64;
    int c0 = blockIdx.x * 64;
    int t = threadIdx.x;
    int rr = t >> 4, c4 = (t & 15) * 4;
#pragma unroll
    for (int i = 0; i < 4; ++i) {
        short4 v = *(const short4*)((const short*)in + (size_t)(r0 + rr + i * 16) * C + c0 + c4);
        lt[rr + i * 16][c4] = v.x; lt[rr + i * 16][c4 + 1] = v.y;
        lt[rr + i * 16][c4 + 2] = v.z; lt[rr + i * 16][c4 + 3] = v.w;
    }
    __syncthreads();
#pragma unroll
    for (int i = 0; i < 4; ++i) {
        int c = rr + i * 16;          // column of in = row of out
        short4 v;
        v.x = lt[c4 + 0][c]; v.y = lt[c4 + 1][c];
        v.z = lt[c4 + 2][c]; v.w = lt[c4 + 3][c];
        *(short4*)((short*)out + (size_t)(c0 + c) * R + r0 + c4) = v;
    }
}

// ---------------- partial reduce: out = base + sum(parts[p]) ----------------
template <int NP>
__global__ __launch_bounds__(256) void reduce_k(const float* __restrict__ base,
                                                const float* __restrict__ parts,
                                                float* __restrict__ out, size_t n) {
    size_t i = ((size_t)blockIdx.x * 256 + threadIdx.x) * 4;
    if (i >= n) return;
    float4 acc = *(const float4*)(base + i);
#pragma unroll
    for (int p = 0; p < NP; ++p) {
        float4 v = *(const float4*)(parts + (size_t)p * n + i);
        acc.x += v.x; acc.y += v.y; acc.z += v.z; acc.w += v.w;
    }
    *(float4*)(out + i) = acc;
}

// ---------------- fused: out = x + p0 + p1 ; xn = rmsnorm(out) ----------------
__global__ __launch_bounds__(256) void reduce2_rms_k(const float* __restrict__ x,
                                                     const float* __restrict__ parts,
                                                     float* __restrict__ out,
                                                     bf16* __restrict__ xn) {
    int row = blockIdx.x;
    int t = threadIdx.x;
    const size_t n = (size_t)T_SEQ * DMODEL;
    const float* xr = x + (size_t)row * DMODEL;
    const float* p0 = parts + (size_t)row * DMODEL;
    const float* p1 = parts + n + (size_t)row * DMODEL;
    float v[8];
    float ss = 0.f;
#pragma unroll
    for (int i = 0; i < 8; ++i) {
        int c = t + i * 256;
        v[i] = xr[c] + p0[c] + p1[c];
        ss += v[i] * v[i];
    }
#pragma unroll
    for (int o = 32; o > 0; o >>= 1) ss += __shfl_xor(ss, o, 64);
    __shared__ float wsum[4];
    int wave = t >> 6;
    if ((t & 63) == 0) wsum[wave] = ss;
    __syncthreads();
    ss = wsum[0] + wsum[1] + wsum[2] + wsum[3];
    float sc = rsqrtf(ss * (1.0f / DMODEL) + RMS_EPS);
    float* orow = out + (size_t)row * DMODEL;
    bf16* nrow = xn + (size_t)row * DMODEL;
#pragma unroll
    for (int i = 0; i < 8; ++i) {
        int c = t + i * 256;
        orow[c] = v[i];
        nrow[c] = f2bf(v[i] * sc);
    }
}

// ---------------- GEMM: C(MxN) = A(MxK) * B(NxK)^T, bf16 in, fp32 acc ----------------
// 128x128 tile, BK=64, 4 waves, each wave 64x64 via 2x2 mfma_32x32x16 subtiles.
// EPI: 0 = fp32 split-K partial (offset blockIdx.z*M*N), 2 = bf16 relu^2, 3 = bf16 plain
// LDS XOR swizzle: LDS[r][p] = G[r][p ^ (r&7)], chunk = 8 shorts (16B).
template <int EPI>
__global__ __launch_bounds__(256) void gemm_bt(const bf16* __restrict__ A,
                                               const bf16* __restrict__ B,
                                               float* __restrict__ Cf,
                                               bf16* __restrict__ Cb,
                                               int M, int N, int K, int Klen) {
    __shared__ alignas(16) short lA[128 * 64];
    __shared__ alignas(16) short lB[128 * 64];
    int t = threadIdx.x;
    int wave = t >> 6, lane = t & 63;
    int m0 = blockIdx.y * 128, n0 = blockIdx.x * 128;
    int wm = (wave >> 1) * 64, wn = (wave & 1) * 64;
    int l31 = lane & 31, kh = lane >> 5;

    f32x16 acc[2][2];
#pragma unroll
    for (int i = 0; i < 2; ++i)
#pragma unroll
        for (int j = 0; j < 2; ++j) acc[i][j] = (f32x16)0.0f;

    // staging: 4 issues per operand per tile; issue i covers rows i*32 + wave*8 .. +7
    int rsub = lane >> 3;
    int scol = ((lane & 7) ^ rsub) * 8;
    const bf16* gA = A + (size_t)(m0 + wave * 8 + rsub) * K + scol;
    const bf16* gB = B + (size_t)(n0 + wave * 8 + rsub) * K + scol;
    short* dA = lA + (wave * 8) * 64;
    short* dB = lB + (wave * 8) * 64;
    size_t rowstep = (size_t)32 * K;

    int swz = lane & 7;
    int kbeg = blockIdx.z * Klen;
    for (int k0 = kbeg; k0 < kbeg + Klen; k0 += 64) {
#pragma unroll
        for (int i = 0; i < 4; ++i) async16(gA + i * rowstep + k0, dA + i * 2048);
#pragma unroll
        for (int i = 0; i < 4; ++i) async16(gB + i * rowstep + k0, dB + i * 2048);
        __syncthreads();
#pragma unroll
        for (int ks = 0; ks < 4; ++ks) {
            int g = ((ks * 2 + kh) ^ swz) * 8;
            bf16x8 a0 = *(const bf16x8*)&lA[(wm + l31) * 64 + g];
            bf16x8 a1 = *(const bf16x8*)&lA[(wm + 32 + l31) * 64 + g];
            bf16x8 b0 = *(const bf16x8*)&lB[(wn + l31) * 64 + g];
            bf16x8 b1 = *(const bf16x8*)&lB[(wn + 32 + l31) * 64 + g];
            acc[0][0] = __builtin_amdgcn_mfma_f32_32x32x16_bf16(a0, b0, acc[0][0], 0, 0, 0);
            acc[0][1] = __builtin_amdgcn_mfma_f32_32x32x16_bf16(a0, b1, acc[0][1], 0, 0, 0);
            acc[1][0] = __builtin_amdgcn_mfma_f32_32x32x16_bf16(a1, b0, acc[1][0], 0, 0, 0);
            acc[1][1] = __builtin_amdgcn_mfma_f32_32x32x16_bf16(a1, b1, acc[1][1], 0, 0, 0);
        }
        __syncthreads();
    }

    // C/D layout (32x32): col = lane&31, row = (reg&3) + 8*(reg>>2) + 4*(lane>>5)
    float* Cpart = (EPI == 0) ? Cf + (size_t)blockIdx.z * M * N : Cf;
#pragma unroll
    for (int mi = 0; mi < 2; ++mi)
#pragma unroll
        for (int ni = 0; ni < 2; ++ni)
#pragma unroll
            for (int gq = 0; gq < 4; ++gq)
#pragma unroll
                for (int r = 0; r < 4; ++r) {
                    int reg = gq * 4 + r;
                    int row = m0 + wm + mi * 32 + r + 8 * gq + 4 * kh;
                    int col = n0 + wn + ni * 32 + l31;
                    float v = acc[mi][ni][reg];
                    size_t idx = (size_t)row * N + col;
                    if (EPI == 0) {
                        Cpart[idx] = v;
                    } else if (EPI == 2) {
                        float rv = fmaxf(v, 0.f);
                        Cb[idx] = f2bf(rv * rv);
                    } else {
                        Cb[idx] = f2bf(v);
                    }
                }
}

// ---------------- attention + ve gates (sigmoid of xn . w_h) ----------------
__global__ __launch_bounds__(256) void gates_k(const bf16* __restrict__ xn,
                                               const float* __restrict__ agw,
                                               const float* __restrict__ vgw,
                                               float* __restrict__ ag,
                                               float* __restrict__ vg) {
    int trow = blockIdx.x;
    __shared__ float xr[DMODEL];
    int t = threadIdx.x;
#pragma unroll
    for (int i = 0; i < 8; ++i) xr[t + i * 256] = bf2f(xn[(size_t)trow * DMODEL + t + i * 256]);
    __syncthreads();
    int wave = t >> 6, lane = t & 63;
#pragma unroll
    for (int hh = 0; hh < 4; ++hh) {
        int h = wave * 4 + hh;
        float sa = 0.f, sv = 0.f;
        for (int d = lane; d < DMODEL; d += 64) {
            float xv = xr[d];
            sa += xv * agw[h * DMODEL + d];
            sv += xv * vgw[h * DMODEL + d];
        }
#pragma unroll
        for (int o = 32; o > 0; o >>= 1) {
            sa += __shfl_xor(sa, o, 64);
            sv += __shfl_xor(sv, o, 64);
        }
        if (lane == 0) {
            ag[trow * NHEADS + h] = 1.f / (1.f + __expf(-sa));
            vg[trow * NHEADS + h] = 1.f / (1.f + __expf(-sv));
        }
    }
}

// ---------------- qkv post-processing: rmsnorm+rope; v += gate*ve (T-major out) ----------------
__global__ __launch_bounds__(256) void qkvproc_k(const bf16* __restrict__ qkv,
                                                 const float* __restrict__ cosb,
                                                 const float* __restrict__ sinb,
                                                 const float* __restrict__ ve,
                                                 const float* __restrict__ vg,
                                                 bf16* __restrict__ qp,
                                                 bf16* __restrict__ kp,
                                                 bf16* __restrict__ vtmp) {
    int trow = blockIdx.x;
    int wave = threadIdx.x >> 6, lane = threadIdx.x & 63;
    const bf16* base = qkv + (size_t)trow * (3 * DMODEL);
    float c = cosb[trow * 64 + lane], s = sinb[trow * 64 + lane];
#pragma unroll
    for (int hh = 0; hh < 4; ++hh) {
        int h = wave * 4 + hh;
        float q0 = bf2f(base[h * HDIM + lane]), q1 = bf2f(base[h * HDIM + lane + 64]);
        float k0 = bf2f(base[DMODEL + h * HDIM + lane]), k1 = bf2f(base[DMODEL + h * HDIM + lane + 64]);
        float v0 = bf2f(base[2 * DMODEL + h * HDIM + lane]), v1 = bf2f(base[2 * DMODEL + h * HDIM + lane + 64]);
        float ssq = q0 * q0 + q1 * q1, ssk = k0 * k0 + k1 * k1;
#pragma unroll
        for (int o = 32; o > 0; o >>= 1) {
            ssq += __shfl_xor(ssq, o, 64);
            ssk += __shfl_xor(ssk, o, 64);
        }
        float scq = rsqrtf(ssq * (1.f / HDIM) + RMS_EPS);
        float sck = rsqrtf(ssk * (1.f / HDIM) + RMS_EPS);
        q0 *= scq; q1 *= scq; k0 *= sck; k1 *= sck;
        float qo0 = q0 * c + q1 * s, qo1 = -q0 * s + q1 * c;
        float ko0 = k0 * c + k1 * s, ko1 = -k0 * s + k1 * c;
        size_t o = ((size_t)h * T_SEQ + trow) * HDIM + lane;
        qp[o] = f2bf(qo0); qp[o + 64] = f2bf(qo1);
        kp[o] = f2bf(ko0); kp[o + 64] = f2bf(ko1);
        float g = vg[trow * NHEADS + h];
        v0 += g * ve[(size_t)trow * DMODEL + h * HDIM + lane];
        v1 += g * ve[(size_t)trow * DMODEL + h * HDIM + lane + 64];
        vtmp[(size_t)trow * DMODEL + h * HDIM + lane] = f2bf(v0);
        vtmp[(size_t)trow * DMODEL + h * HDIM + lane + 64] = f2bf(v1);
    }
}

// ---------------- flash attention (doc-masked causal), key-shift during staging ----------------
__global__ __launch_bounds__(256) void fattn_k(const bf16* __restrict__ qp,
                                               const bf16* __restrict__ kp,
                                               const bf16* __restrict__ vp,
                                               const int* __restrict__ docs,
                                               const float* __restrict__ scale_p,
                                               const float* __restrict__ ag,
                                               const int* __restrict__ keyoff,
                                               bf16* __restrict__ y) {
    int h = blockIdx.y;
    int q0 = blockIdx.x * 64;
    int t = threadIdx.x, wave = t >> 6, lane = t & 63;
    int lr = lane & 15, kq = lane >> 4;
    __shared__ alignas(16) short sQ[64 * 128];
    __shared__ alignas(16) short sK[64 * 128];
    __shared__ alignas(16) short sV[128 * 64];
    __shared__ alignas(16) short sP[4][16 * 64];

    const bf16* qh = qp + (size_t)h * T_SEQ * HDIM;
    const bf16* kh = kp + (size_t)h * T_SEQ * HDIM;
    const bf16* vh = vp + (size_t)h * HDIM * T_SEQ;
    int ko = keyoff[0];

    {
        int srow = wave * 4 + (lane >> 4);
        int scq = (lane & 15) * 8;
#pragma unroll
        for (int i = 0; i < 4; ++i)
            async16(qh + (size_t)(q0 + i * 16 + srow) * HDIM + scq, &sQ[(i * 16 + wave * 4) * HDIM]);
    }
    __syncthreads();
    bf16x8 qf[4];
#pragma unroll
    for (int kk = 0; kk < 4; ++kk)
        qf[kk] = *(const bf16x8*)&sQ[(wave * 16 + lr) * HDIM + kk * 32 + kq * 8];

    float scl = scale_p[0];
    int myq[4], mydoc[4];
#pragma unroll
    for (int r = 0; r < 4; ++r) {
        myq[r] = q0 + wave * 16 + kq * 4 + r;
        mydoc[r] = docs[myq[r]];
    }
    float m_i[4], l_i[4];
#pragma unroll
    for (int r = 0; r < 4; ++r) { m_i[r] = -1e30f; l_i[r] = 0.f; }
    f32x4 oacc[8];
#pragma unroll
    for (int i = 0; i < 8; ++i) oacc[i] = (f32x4)0.f;

    int dq0 = docs[q0];
    int lo = 0, hi = q0;
    while (lo < hi) { int mid = (lo + hi) >> 1; if (docs[mid] < dq0) lo = mid + 1; else hi = mid; }
    int s_begin = lo & ~63;

    for (int s0 = s_begin; s0 <= q0; s0 += 64) {
        {
            int rbase = wave * 4 + (lane >> 4);
            int scq = (lane & 15) * 8;
            int band = (scq >> 5) & 1;
#pragma unroll
            for (int i = 0; i < 4; ++i) {
                int g = s0 + i * 16 + rbase;
                int ts = (ko && band && g > 0) ? g - 1 : g;
                async16(kh + (size_t)ts * HDIM + scq, &sK[(i * 16 + wave * 4) * HDIM]);
            }
            int vrow = wave * 8 + (lane >> 3);
            int vcq = (lane & 7) * 8;
#pragma unroll
            for (int i = 0; i < 4; ++i)
                async16(vh + (size_t)(i * 32 + vrow) * T_SEQ + s0 + vcq, &sV[(i * 32 + wave * 8) * 64]);
        }
        __syncthreads();

        f32x4 sc[4];
#pragma unroll
        for (int ni = 0; ni < 4; ++ni) {
            sc[ni] = (f32x4)0.f;
#pragma unroll
            for (int kk = 0; kk < 4; ++kk) {
                bf16x8 bfrag = *(const bf16x8*)&sK[(ni * 16 + lr) * HDIM + kk * 32 + kq * 8];
                sc[ni] = __builtin_amdgcn_mfma_f32_16x16x32_bf16(qf[kk], bfrag, sc[ni], 0, 0, 0);
            }
        }
        float pv[4][4];
        float mt[4];
#pragma unroll
        for (int r = 0; r < 4; ++r) mt[r] = -1e30f;
#pragma unroll
        for (int ni = 0; ni < 4; ++ni) {
            int scol = s0 + ni * 16 + lr;
            int sdoc = docs[scol];
#pragma unroll
            for (int r = 0; r < 4; ++r) {
                float v = sc[ni][r] * scl;
                if (scol > myq[r] || sdoc != mydoc[r]) v = -1e30f;
                pv[ni][r] = v;
                mt[r] = fmaxf(mt[r], v);
            }
        }
#pragma unroll
        for (int r = 0; r < 4; ++r) {
#pragma unroll
            for (int o = 1; o < 16; o <<= 1) mt[r] = fmaxf(mt[r], __shfl_xor(mt[r], o, 64));
        }
        float alpha[4], rsum[4];
#pragma unroll
        for (int r = 0; r < 4; ++r) {
            float mnew = fmaxf(m_i[r], mt[r]);
            alpha[r] = __expf(m_i[r] - mnew);
            m_i[r] = mnew;
            rsum[r] = 0.f;
        }
#pragma unroll
        for (int ni = 0; ni < 4; ++ni)
#pragma unroll
            for (int r = 0; r < 4; ++r) {
                float p = __expf(pv[ni][r] - m_i[r]);
                pv[ni][r] = p;
                rsum[r] += p;
            }
#pragma unroll
        for (int r = 0; r < 4; ++r) {
#pragma unroll
            for (int o = 1; o < 16; o <<= 1) rsum[r] += __shfl_xor(rsum[r], o, 64);
            l_i[r] = l_i[r] * alpha[r] + rsum[r];
        }
#pragma unroll
        for (int i = 0; i < 8; ++i)
#pragma unroll
            for (int r = 0; r < 4; ++r) oacc[i][r] *= alpha[r];

#pragma unroll
        for (int ni = 0; ni < 4; ++ni)
#pragma unroll
            for (int r = 0; r < 4; ++r) {
                bf16 b = f2bf(pv[ni][r]);
                sP[wave][(kq * 4 + r) * 64 + ni * 16 + lr] = *(short*)&b;
            }
        bf16x8 pf[2];
#pragma unroll
        for (int kk = 0; kk < 2; ++kk)
            pf[kk] = *(const bf16x8*)&sP[wave][lr * 64 + kk * 32 + kq * 8];
#pragma unroll
        for (int oi = 0; oi < 8; ++oi) {
#pragma unroll
            for (int kk = 0; kk < 2; ++kk) {
                bf16x8 vfrag = *(const bf16x8*)&sV[(oi * 16 + lr) * 64 + kk * 32 + kq * 8];
                oacc[oi] = __builtin_amdgcn_mfma_f32_16x16x32_bf16(pf[kk], vfrag, oacc[oi], 0, 0, 0);
            }
        }
        __syncthreads();
    }

#pragma unroll
    for (int r = 0; r < 4; ++r) {
        int row = myq[r];
        float g = ag[row * NHEADS + h];
        float inv = g / l_i[r];
#pragma unroll
        for (int oi = 0; oi < 8; ++oi)
            y[(size_t)row * DMODEL + h * HDIM + oi * 16 + lr] = f2bf(oacc[oi][r] * inv);
    }
}

extern "C" void kernel_launch(void* const* d_in, const int* in_sizes, int n_in,
                              void* d_out, int out_size, void* d_ws, size_t ws_size,
                              hipStream_t stream) {
    (void)in_sizes; (void)n_in; (void)out_size; (void)ws_size;
    const float* x      = (const float*)d_in[0];
    const float* ve     = (const float*)d_in[1];
    const float* qkvo_w = (const float*)d_in[2];
    const float* agw    = (const float*)d_in[3];
    const float* vgw    = (const float*)d_in[4];
    const float* c_fc   = (const float*)d_in[5];
    const float* c_proj = (const float*)d_in[6];
    const float* lam    = (const float*)d_in[7];
    const float* cosb   = (const float*)d_in[8];
    const float* sinb   = (const float*)d_in[9];
    const float* ascale = (const float*)d_in[10];
    const int*   docs   = (const int*)d_in[11];
    const int*   keyoff = (const int*)d_in[12];
    float* out = (float*)d_out;

    char* ws = (char*)d_ws;
    size_t off = 0;
    auto alloc = [&](size_t bytes) {
        char* p = ws + off;
        off += (bytes + 255) & ~(size_t)255;
        return p;
    };
    bf16*  xn     = (bf16*)alloc((size_t)T_SEQ * DMODEL * 2);
    // wqkv+wo+wfc region (67.1 MB); PROJ split-4 partials alias it in step 10.
    char*  wregion = alloc((size_t)3 * DMODEL * DMODEL * 2 +
                           (size_t)DMODEL * DMODEL * 2 +
                           (size_t)FFN_D * DMODEL * 2);
    bf16*  wqkv   = (bf16*)wregion;
    bf16*  wo     = (bf16*)(wregion + (size_t)3 * DMODEL * DMODEL * 2);
    bf16*  wfc    = (bf16*)(wregion + (size_t)4 * DMODEL * DMODEL * 2);
    float* projpart = (float*)wregion;
    bf16*  wprojT = (bf16*)alloc((size_t)DMODEL * FFN_D * 2);
    char*  qkvreg = alloc((size_t)T_SEQ * 3 * DMODEL * 4);    // 50.3 MB region
    bf16*  qkvb   = (bf16*)qkvreg;                            // steps 3-5 (25.2 MB)
    float* opart  = (float*)qkvreg;                           // 2 partials (33.5MB), step 7
    bf16*  hbuf   = (bf16*)qkvreg;                            // steps 9-10 (33.5 MB)
    bf16*  ybuf   = (bf16*)(qkvreg + (size_t)T_SEQ * FFN_D * 2); // steps 6-7 (8.4 MB)
    bf16*  qp     = (bf16*)alloc((size_t)NHEADS * T_SEQ * HDIM * 2);
    bf16*  kp     = (bf16*)alloc((size_t)NHEADS * T_SEQ * HDIM * 2);
    bf16*  vp     = (bf16*)alloc((size_t)NHEADS * HDIM * T_SEQ * 2);
    bf16*  vtmp   = (bf16*)alloc((size_t)T_SEQ * DMODEL * 2);
    float* agate  = (float*)alloc((size_t)T_SEQ * NHEADS * 4);
    float* vgate  = (float*)alloc((size_t)T_SEQ * NHEADS * 4);

    const size_t NN = (size_t)T_SEQ * DMODEL;

    // 1. xn = rmsnorm(x)
    rmsnorm_k<<<T_SEQ, 256, 0, stream>>>(x, xn);
    // 2. weight converts
    convert_k<<<(3 * DMODEL * DMODEL) / 1024, 256, 0, stream>>>(qkvo_w, wqkv, lam, 0, (size_t)3 * DMODEL * DMODEL);
    convert_k<<<(DMODEL * DMODEL) / 1024, 256, 0, stream>>>(qkvo_w + (size_t)3 * DMODEL * DMODEL, wo, lam, 1, (size_t)DMODEL * DMODEL);
    convert_k<<<(FFN_D * DMODEL) / 1024, 256, 0, stream>>>(c_fc, wfc, nullptr, 0, (size_t)FFN_D * DMODEL);
    transpose_convert_k<<<dim3(FFN_D / 32, DMODEL / 32), 256, 0, stream>>>(c_proj, wprojT);
    // 3. qkv = xn @ wqkv^T  (bf16 out)
    gemm_bt<3><<<dim3(3 * DMODEL / 128, T_SEQ / 128, 1), 256, 0, stream>>>(xn, wqkv, nullptr, qkvb, T_SEQ, 3 * DMODEL, DMODEL, DMODEL);
    // 4. gates
    gates_k<<<T_SEQ, 256, 0, stream>>>(xn, agw, vgw, agate, vgate);
    // 5. q/k rmsnorm+rope, v += gate*ve (vtmp T-major)
    qkvproc_k<<<T_SEQ, 256, 0, stream>>>(qkvb, cosb, sinb, ve, vgate, qp, kp, vtmp);
    // 5b. vp = vtmp^T  (T x D -> D x T, D rows map to (h,hd))
    transpose16_k<<<dim3(DMODEL / 64, T_SEQ / 64), 256, 0, stream>>>(vtmp, vp, T_SEQ, DMODEL);
    // 6. attention
    fattn_k<<<dim3(T_SEQ / 64, NHEADS), 256, 0, stream>>>(qp, kp, vp, docs, ascale, agate, keyoff, ybuf);
    // 7. attn proj, split-K=2 -> partials
    gemm_bt<0><<<dim3(DMODEL / 128, T_SEQ / 128, 2), 256, 0, stream>>>(ybuf, wo, opart, nullptr, T_SEQ, DMODEL, DMODEL, DMODEL / 2);
    // 8. out = x + p0 + p1 ; xn = rmsnorm(out)
    reduce2_rms_k<<<T_SEQ, 256, 0, stream>>>(x, opart, out, xn);
    // 9. h = relu(xn2 @ wfc^T)^2 -> bf16
    gemm_bt<2><<<dim3(FFN_D / 128, T_SEQ / 128, 1), 256, 0, stream>>>(xn, wfc, nullptr, hbuf, T_SEQ, FFN_D, DMODEL, DMODEL);
    // 10. mlp proj, split-K=4 -> partials; then out += p0..p3
    gemm_bt<0><<<dim3(DMODEL / 128, T_SEQ / 128, 4), 256, 0, stream>>>(hbuf, wprojT, projpart, nullptr, T_SEQ, DMODEL, FFN_D, FFN_D / 4);
    reduce_k<4><<<NN / 1024, 256, 0, stream>>>(out, projpart, out, NN);
}

// Round 5
// 631.699 us; speedup vs baseline: 1.3050x; 1.0166x over previous
//
#include <hip/hip_runtime.h>
#include <hip/hip_bf16.h>

#define T_SEQ 2048
#define DMODEL 2048
#define NHEADS 16
#define HDIM 128
#define FFN_D 8192
#define RMS_EPS 1.1920929e-7f

typedef __hip_bfloat16 bf16;
using bf16x8 = __attribute__((ext_vector_type(8))) short;
using f32x4  = __attribute__((ext_vector_type(4))) float;
using f32x16 = __attribute__((ext_vector_type(16))) float;

__device__ __forceinline__ float bf2f(bf16 v) { return __bfloat162float(v); }
__device__ __forceinline__ bf16  f2bf(float v) { return __float2bfloat16(v); }

__device__ __forceinline__ void async16(const void* g, void* l) {
    __builtin_amdgcn_global_load_lds(
        (const __attribute__((address_space(1))) void*)g,
        (__attribute__((address_space(3))) void*)l,
        16, 0, 0);
}

// ---------------- RMSNorm: fp32 row -> bf16 row ----------------
__global__ __launch_bounds__(256) void rmsnorm_k(const float* __restrict__ x,
                                                 bf16* __restrict__ out) {
    int row = blockIdx.x;
    const float* xr = x + (size_t)row * DMODEL;
    int t = threadIdx.x;
    float v[8];
    float ss = 0.f;
#pragma unroll
    for (int i = 0; i < 8; ++i) { v[i] = xr[t + i * 256]; ss += v[i] * v[i]; }
#pragma unroll
    for (int o = 32; o > 0; o >>= 1) ss += __shfl_xor(ss, o, 64);
    __shared__ float wsum[4];
    int wave = t >> 6;
    if ((t & 63) == 0) wsum[wave] = ss;
    __syncthreads();
    ss = wsum[0] + wsum[1] + wsum[2] + wsum[3];
    float sc = rsqrtf(ss * (1.0f / DMODEL) + RMS_EPS);
    bf16* orow = out + (size_t)row * DMODEL;
#pragma unroll
    for (int i = 0; i < 8; ++i) orow[t + i * 256] = f2bf(v[i] * sc);
}

// ---------------- convert qkvo (lam[0] for first 3DD, lam[1] for last DD) ----------------
__global__ __launch_bounds__(256) void convert_qkvo_k(const float* __restrict__ in,
                                                      bf16* __restrict__ out,
                                                      const float* __restrict__ lam) {
    const size_t n3 = (size_t)3 * DMODEL * DMODEL;
    size_t i = (size_t)blockIdx.x * 1024 + (size_t)threadIdx.x * 4;
    float s = (i < n3) ? lam[0] : lam[1];
    float4 f = *(const float4*)(in + i);
    bf16 h0 = f2bf(f.x * s), h1 = f2bf(f.y * s), h2 = f2bf(f.z * s), h3 = f2bf(f.w * s);
    short4 o;
    o.x = *(short*)&h0; o.y = *(short*)&h1; o.z = *(short*)&h2; o.w = *(short*)&h3;
    *(short4*)((short*)out + i) = o;
}

// ---------------- plain convert fp32 -> bf16 ----------------
__global__ __launch_bounds__(256) void convert_k(const float* __restrict__ in,
                                                 bf16* __restrict__ out, size_t n) {
    size_t i = (size_t)blockIdx.x * 1024 + (size_t)threadIdx.x * 4;
    if (i + 3 < n) {
        float4 f = *(const float4*)(in + i);
        bf16 h0 = f2bf(f.x), h1 = f2bf(f.y), h2 = f2bf(f.z), h3 = f2bf(f.w);
        short4 o;
        o.x = *(short*)&h0; o.y = *(short*)&h1; o.z = *(short*)&h2; o.w = *(short*)&h3;
        *(short4*)((short*)out + i) = o;
    }
}

// ---------------- transpose + convert: c_proj (FFN x D) -> (D x FFN) bf16 ----------------
__global__ __launch_bounds__(256) void transpose_convert_k(const float* __restrict__ in,
                                                           bf16* __restrict__ out) {
    __shared__ float tile[32][33];
    int f0 = blockIdx.x * 32;
    int d0 = blockIdx.y * 32;
    int tx = threadIdx.x & 31, ty = threadIdx.x >> 5;
#pragma unroll
    for (int i = 0; i < 32; i += 8)
        tile[ty + i][tx] = in[(size_t)(f0 + ty + i) * DMODEL + d0 + tx];
    __syncthreads();
#pragma unroll
    for (int i = 0; i < 32; i += 8)
        out[(size_t)(d0 + ty + i) * FFN_D + f0 + tx] = f2bf(tile[tx][ty + i]);
}

// ---------------- bf16 transpose: in (R x C) -> out (C x R), 64x64 tiles ----------------
__global__ __launch_bounds__(256) void transpose16_k(const bf16* __restrict__ in,
                                                     bf16* __restrict__ out,
                                                     int R, int C) {
    __shared__ short lt[64][68];
    int r0 = blockIdx.y * 64;
    int c0 = blockIdx.x * 64;
    int t = threadIdx.x;
    int rr = t >> 4, c4 = (t & 15) * 4;
#pragma unroll
    for (int i = 0; i < 4; ++i) {
        short4 v = *(const short4*)((const short*)in + (size_t)(r0 + rr + i * 16) * C + c0 + c4);
        lt[rr + i * 16][c4] = v.x; lt[rr + i * 16][c4 + 1] = v.y;
        lt[rr + i * 16][c4 + 2] = v.z; lt[rr + i * 16][c4 + 3] = v.w;
    }
    __syncthreads();
#pragma unroll
    for (int i = 0; i < 4; ++i) {
        int c = rr + i * 16;
        short4 v;
        v.x = lt[c4 + 0][c]; v.y = lt[c4 + 1][c];
        v.z = lt[c4 + 2][c]; v.w = lt[c4 + 3][c];
        *(short4*)((short*)out + (size_t)(c0 + c) * R + r0 + c4) = v;
    }
}

// ---------------- partial reduce: out = base + sum(parts[p]) ----------------
template <int NP>
__global__ __launch_bounds__(256) void reduce_k(const float* __restrict__ base,
                                                const float* __restrict__ parts,
                                                float* __restrict__ out, size_t n) {
    size_t i = ((size_t)blockIdx.x * 256 + threadIdx.x) * 4;
    if (i >= n) return;
    float4 acc = *(const float4*)(base + i);
#pragma unroll
    for (int p = 0; p < NP; ++p) {
        float4 v = *(const float4*)(parts + (size_t)p * n + i);
        acc.x += v.x; acc.y += v.y; acc.z += v.z; acc.w += v.w;
    }
    *(float4*)(out + i) = acc;
}

// ---------------- fused: out = x + p0 + p1 ; xn = rmsnorm(out) ----------------
__global__ __launch_bounds__(256) void reduce2_rms_k(const float* __restrict__ x,
                                                     const float* __restrict__ parts,
                                                     float* __restrict__ out,
                                                     bf16* __restrict__ xn) {
    int row = blockIdx.x;
    int t = threadIdx.x;
    const size_t n = (size_t)T_SEQ * DMODEL;
    const float* xr = x + (size_t)row * DMODEL;
    const float* p0 = parts + (size_t)row * DMODEL;
    const float* p1 = parts + n + (size_t)row * DMODEL;
    float v[8];
    float ss = 0.f;
#pragma unroll
    for (int i = 0; i < 8; ++i) {
        int c = t + i * 256;
        v[i] = xr[c] + p0[c] + p1[c];
        ss += v[i] * v[i];
    }
#pragma unroll
    for (int o = 32; o > 0; o >>= 1) ss += __shfl_xor(ss, o, 64);
    __shared__ float wsum[4];
    int wave = t >> 6;
    if ((t & 63) == 0) wsum[wave] = ss;
    __syncthreads();
    ss = wsum[0] + wsum[1] + wsum[2] + wsum[3];
    float sc = rsqrtf(ss * (1.0f / DMODEL) + RMS_EPS);
    float* orow = out + (size_t)row * DMODEL;
    bf16* nrow = xn + (size_t)row * DMODEL;
#pragma unroll
    for (int i = 0; i < 8; ++i) {
        int c = t + i * 256;
        orow[c] = v[i];
        nrow[c] = f2bf(v[i] * sc);
    }
}

// ---------------- GEMM: C(MxN) = A(MxK) * B(NxK)^T, bf16 in, fp32 acc ----------------
// 128x128 tile, BK=64, double-buffered LDS (one barrier/iter), 4 waves,
// each wave 64x64 via 2x2 mfma_32x32x16.  Pipeline: barrier -> issue tile k+1
// into buf^1 -> compute tile k from buf (loads fly during compute).
// EPI: 0 = fp32 split-K partial, 2 = bf16 relu^2, 3 = bf16 plain
template <int EPI>
__global__ __launch_bounds__(256) void gemm_bt(const bf16* __restrict__ A,
                                               const bf16* __restrict__ B,
                                               float* __restrict__ Cf,
                                               bf16* __restrict__ Cb,
                                               int M, int N, int K, int Klen) {
    __shared__ alignas(16) short lAB[2][2][128 * 64];   // [buf][A/B]
    int t = threadIdx.x;
    int wave = t >> 6, lane = t & 63;
    int m0 = blockIdx.y * 128, n0 = blockIdx.x * 128;
    int wm = (wave >> 1) * 64, wn = (wave & 1) * 64;
    int l31 = lane & 31, kh = lane >> 5;

    f32x16 acc[2][2];
#pragma unroll
    for (int i = 0; i < 2; ++i)
#pragma unroll
        for (int j = 0; j < 2; ++j) acc[i][j] = (f32x16)0.0f;

    int rsub = lane >> 3;
    int scol = ((lane & 7) ^ rsub) * 8;            // XOR-swizzled source chunk
    const bf16* gA = A + (size_t)(m0 + wave * 8 + rsub) * K + scol;
    const bf16* gB = B + (size_t)(n0 + wave * 8 + rsub) * K + scol;
    size_t rowstep = (size_t)32 * K;

    int kbeg = blockIdx.z * Klen;
    int nk = Klen / 64;
    int swz = lane & 7;

    // prologue: stage tile 0 into buf 0
    {
        short* dA = &lAB[0][0][wave * 512];
        short* dB = &lAB[0][1][wave * 512];
#pragma unroll
        for (int i = 0; i < 4; ++i) async16(gA + i * rowstep + kbeg, dA + i * 2048);
#pragma unroll
        for (int i = 0; i < 4; ++i) async16(gB + i * rowstep + kbeg, dB + i * 2048);
    }

    for (int it = 0; it < nk; ++it) {
        __syncthreads();                            // drains vmcnt: buf[it&1] ready
        if (it + 1 < nk) {                          // prefetch next tile into other buf
            int k1 = kbeg + (it + 1) * 64;
            short* dA = &lAB[(it + 1) & 1][0][wave * 512];
            short* dB = &lAB[(it + 1) & 1][1][wave * 512];
#pragma unroll
            for (int i = 0; i < 4; ++i) async16(gA + i * rowstep + k1, dA + i * 2048);
#pragma unroll
            for (int i = 0; i < 4; ++i) async16(gB + i * rowstep + k1, dB + i * 2048);
        }
        const short* cA = lAB[it & 1][0];
        const short* cB = lAB[it & 1][1];
#pragma unroll
        for (int ks = 0; ks < 4; ++ks) {
            int g = ((ks * 2 + kh) ^ swz) * 8;
            bf16x8 a0 = *(const bf16x8*)&cA[(wm + l31) * 64 + g];
            bf16x8 a1 = *(const bf16x8*)&cA[(wm + 32 + l31) * 64 + g];
            bf16x8 b0 = *(const bf16x8*)&cB[(wn + l31) * 64 + g];
            bf16x8 b1 = *(const bf16x8*)&cB[(wn + 32 + l31) * 64 + g];
            acc[0][0] = __builtin_amdgcn_mfma_f32_32x32x16_bf16(a0, b0, acc[0][0], 0, 0, 0);
            acc[0][1] = __builtin_amdgcn_mfma_f32_32x32x16_bf16(a0, b1, acc[0][1], 0, 0, 0);
            acc[1][0] = __builtin_amdgcn_mfma_f32_32x32x16_bf16(a1, b0, acc[1][0], 0, 0, 0);
            acc[1][1] = __builtin_amdgcn_mfma_f32_32x32x16_bf16(a1, b1, acc[1][1], 0, 0, 0);
        }
    }

    // C/D layout (32x32): col = lane&31, row = (reg&3) + 8*(reg>>2) + 4*(lane>>5)
    float* Cpart = (EPI == 0) ? Cf + (size_t)blockIdx.z * M * N : Cf;
#pragma unroll
    for (int mi = 0; mi < 2; ++mi)
#pragma unroll
        for (int ni = 0; ni < 2; ++ni)
#pragma unroll
            for (int gq = 0; gq < 4; ++gq)
#pragma unroll
                for (int r = 0; r < 4; ++r) {
                    int reg = gq * 4 + r;
                    int row = m0 + wm + mi * 32 + r + 8 * gq + 4 * kh;
                    int col = n0 + wn + ni * 32 + l31;
                    float v = acc[mi][ni][reg];
                    size_t idx = (size_t)row * N + col;
                    if (EPI == 0) {
                        Cpart[idx] = v;
                    } else if (EPI == 2) {
                        float rv = fmaxf(v, 0.f);
                        Cb[idx] = f2bf(rv * rv);
                    } else {
                        Cb[idx] = f2bf(v);
                    }
                }
}

// ---------------- attention + ve gates (sigmoid of xn . w_h) ----------------
__global__ __launch_bounds__(256) void gates_k(const bf16* __restrict__ xn,
                                               const float* __restrict__ agw,
                                               const float* __restrict__ vgw,
                                               float* __restrict__ ag,
                                               float* __restrict__ vg) {
    int trow = blockIdx.x;
    __shared__ float xr[DMODEL];
    int t = threadIdx.x;
#pragma unroll
    for (int i = 0; i < 8; ++i) xr[t + i * 256] = bf2f(xn[(size_t)trow * DMODEL + t + i * 256]);
    __syncthreads();
    int wave = t >> 6, lane = t & 63;
#pragma unroll
    for (int hh = 0; hh < 4; ++hh) {
        int h = wave * 4 + hh;
        float sa = 0.f, sv = 0.f;
        for (int d = lane; d < DMODEL; d += 64) {
            float xv = xr[d];
            sa += xv * agw[h * DMODEL + d];
            sv += xv * vgw[h * DMODEL + d];
        }
#pragma unroll
        for (int o = 32; o > 0; o >>= 1) {
            sa += __shfl_xor(sa, o, 64);
            sv += __shfl_xor(sv, o, 64);
        }
        if (lane == 0) {
            ag[trow * NHEADS + h] = 1.f / (1.f + __expf(-sa));
            vg[trow * NHEADS + h] = 1.f / (1.f + __expf(-sv));
        }
    }
}

// ---------------- qkv post-processing: rmsnorm+rope; v += gate*ve (T-major out) ----------------
__global__ __launch_bounds__(256) void qkvproc_k(const bf16* __restrict__ qkv,
                                                 const float* __restrict__ cosb,
                                                 const float* __restrict__ sinb,
                                                 const float* __restrict__ ve,
                                                 const float* __restrict__ vg,
                                                 bf16* __restrict__ qp,
                                                 bf16* __restrict__ kp,
                                                 bf16* __restrict__ vtmp) {
    int trow = blockIdx.x;
    int wave = threadIdx.x >> 6, lane = threadIdx.x & 63;
    const bf16* base = qkv + (size_t)trow * (3 * DMODEL);
    float c = cosb[trow * 64 + lane], s = sinb[trow * 64 + lane];
#pragma unroll
    for (int hh = 0; hh < 4; ++hh) {
        int h = wave * 4 + hh;
        float q0 = bf2f(base[h * HDIM + lane]), q1 = bf2f(base[h * HDIM + lane + 64]);
        float k0 = bf2f(base[DMODEL + h * HDIM + lane]), k1 = bf2f(base[DMODEL + h * HDIM + lane + 64]);
        float v0 = bf2f(base[2 * DMODEL + h * HDIM + lane]), v1 = bf2f(base[2 * DMODEL + h * HDIM + lane + 64]);
        float ssq = q0 * q0 + q1 * q1, ssk = k0 * k0 + k1 * k1;
#pragma unroll
        for (int o = 32; o > 0; o >>= 1) {
            ssq += __shfl_xor(ssq, o, 64);
            ssk += __shfl_xor(ssk, o, 64);
        }
        float scq = rsqrtf(ssq * (1.f / HDIM) + RMS_EPS);
        float sck = rsqrtf(ssk * (1.f / HDIM) + RMS_EPS);
        q0 *= scq; q1 *= scq; k0 *= sck; k1 *= sck;
        float qo0 = q0 * c + q1 * s, qo1 = -q0 * s + q1 * c;
        float ko0 = k0 * c + k1 * s, ko1 = -k0 * s + k1 * c;
        size_t o = ((size_t)h * T_SEQ + trow) * HDIM + lane;
        qp[o] = f2bf(qo0); qp[o + 64] = f2bf(qo1);
        kp[o] = f2bf(ko0); kp[o + 64] = f2bf(ko1);
        float g = vg[trow * NHEADS + h];
        v0 += g * ve[(size_t)trow * DMODEL + h * HDIM + lane];
        v1 += g * ve[(size_t)trow * DMODEL + h * HDIM + lane + 64];
        vtmp[(size_t)trow * DMODEL + h * HDIM + lane] = f2bf(v0);
        vtmp[(size_t)trow * DMODEL + h * HDIM + lane + 64] = f2bf(v1);
    }
}

// ---------------- flash attention (doc-masked causal), key-shift during staging ----------------
__global__ __launch_bounds__(256) void fattn_k(const bf16* __restrict__ qp,
                                               const bf16* __restrict__ kp,
                                               const bf16* __restrict__ vp,
                                               const int* __restrict__ docs,
                                               const float* __restrict__ scale_p,
                                               const float* __restrict__ ag,
                                               const int* __restrict__ keyoff,
                                               bf16* __restrict__ y) {
    int h = blockIdx.y;
    int q0 = blockIdx.x * 64;
    int t = threadIdx.x, wave = t >> 6, lane = t & 63;
    int lr = lane & 15, kq = lane >> 4;
    __shared__ alignas(16) short sQ[64 * 128];
    __shared__ alignas(16) short sK[64 * 128];
    __shared__ alignas(16) short sV[128 * 64];
    __shared__ alignas(16) short sP[4][16 * 64];

    const bf16* qh = qp + (size_t)h * T_SEQ * HDIM;
    const bf16* kh = kp + (size_t)h * T_SEQ * HDIM;
    const bf16* vh = vp + (size_t)h * HDIM * T_SEQ;
    int ko = keyoff[0];

    {
        int srow = wave * 4 + (lane >> 4);
        int scq = (lane & 15) * 8;
#pragma unroll
        for (int i = 0; i < 4; ++i)
            async16(qh + (size_t)(q0 + i * 16 + srow) * HDIM + scq, &sQ[(i * 16 + wave * 4) * HDIM]);
    }
    __syncthreads();
    bf16x8 qf[4];
#pragma unroll
    for (int kk = 0; kk < 4; ++kk)
        qf[kk] = *(const bf16x8*)&sQ[(wave * 16 + lr) * HDIM + kk * 32 + kq * 8];

    float scl = scale_p[0];
    int myq[4], mydoc[4];
#pragma unroll
    for (int r = 0; r < 4; ++r) {
        myq[r] = q0 + wave * 16 + kq * 4 + r;
        mydoc[r] = docs[myq[r]];
    }
    float m_i[4], l_i[4];
#pragma unroll
    for (int r = 0; r < 4; ++r) { m_i[r] = -1e30f; l_i[r] = 0.f; }
    f32x4 oacc[8];
#pragma unroll
    for (int i = 0; i < 8; ++i) oacc[i] = (f32x4)0.f;

    int dq0 = docs[q0];
    int lo = 0, hi = q0;
    while (lo < hi) { int mid = (lo + hi) >> 1; if (docs[mid] < dq0) lo = mid + 1; else hi = mid; }
    int s_begin = lo & ~63;

    for (int s0 = s_begin; s0 <= q0; s0 += 64) {
        {
            int rbase = wave * 4 + (lane >> 4);
            int scq = (lane & 15) * 8;
            int band = (scq >> 5) & 1;
#pragma unroll
            for (int i = 0; i < 4; ++i) {
                int g = s0 + i * 16 + rbase;
                int ts = (ko && band && g > 0) ? g - 1 : g;
                async16(kh + (size_t)ts * HDIM + scq, &sK[(i * 16 + wave * 4) * HDIM]);
            }
            int vrow = wave * 8 + (lane >> 3);
            int vcq = (lane & 7) * 8;
#pragma unroll
            for (int i = 0; i < 4; ++i)
                async16(vh + (size_t)(i * 32 + vrow) * T_SEQ + s0 + vcq, &sV[(i * 32 + wave * 8) * 64]);
        }
        __syncthreads();

        f32x4 sc[4];
#pragma unroll
        for (int ni = 0; ni < 4; ++ni) {
            sc[ni] = (f32x4)0.f;
#pragma unroll
            for (int kk = 0; kk < 4; ++kk) {
                bf16x8 bfrag = *(const bf16x8*)&sK[(ni * 16 + lr) * HDIM + kk * 32 + kq * 8];
                sc[ni] = __builtin_amdgcn_mfma_f32_16x16x32_bf16(qf[kk], bfrag, sc[ni], 0, 0, 0);
            }
        }
        float pv[4][4];
        float mt[4];
#pragma unroll
        for (int r = 0; r < 4; ++r) mt[r] = -1e30f;
#pragma unroll
        for (int ni = 0; ni < 4; ++ni) {
            int scol = s0 + ni * 16 + lr;
            int sdoc = docs[scol];
#pragma unroll
            for (int r = 0; r < 4; ++r) {
                float v = sc[ni][r] * scl;
                if (scol > myq[r] || sdoc != mydoc[r]) v = -1e30f;
                pv[ni][r] = v;
                mt[r] = fmaxf(mt[r], v);
            }
        }
#pragma unroll
        for (int r = 0; r < 4; ++r) {
#pragma unroll
            for (int o = 1; o < 16; o <<= 1) mt[r] = fmaxf(mt[r], __shfl_xor(mt[r], o, 64));
        }
        float alpha[4], rsum[4];
#pragma unroll
        for (int r = 0; r < 4; ++r) {
            float mnew = fmaxf(m_i[r], mt[r]);
            alpha[r] = __expf(m_i[r] - mnew);
            m_i[r] = mnew;
            rsum[r] = 0.f;
        }
#pragma unroll
        for (int ni = 0; ni < 4; ++ni)
#pragma unroll
            for (int r = 0; r < 4; ++r) {
                float p = __expf(pv[ni][r] - m_i[r]);
                pv[ni][r] = p;
                rsum[r] += p;
            }
#pragma unroll
        for (int r = 0; r < 4; ++r) {
#pragma unroll
            for (int o = 1; o < 16; o <<= 1) rsum[r] += __shfl_xor(rsum[r], o, 64);
            l_i[r] = l_i[r] * alpha[r] + rsum[r];
        }
#pragma unroll
        for (int i = 0; i < 8; ++i)
#pragma unroll
            for (int r = 0; r < 4; ++r) oacc[i][r] *= alpha[r];

#pragma unroll
        for (int ni = 0; ni < 4; ++ni)
#pragma unroll
            for (int r = 0; r < 4; ++r) {
                bf16 b = f2bf(pv[ni][r]);
                sP[wave][(kq * 4 + r) * 64 + ni * 16 + lr] = *(short*)&b;
            }
        bf16x8 pf[2];
#pragma unroll
        for (int kk = 0; kk < 2; ++kk)
            pf[kk] = *(const bf16x8*)&sP[wave][lr * 64 + kk * 32 + kq * 8];
#pragma unroll
        for (int oi = 0; oi < 8; ++oi) {
#pragma unroll
            for (int kk = 0; kk < 2; ++kk) {
                bf16x8 vfrag = *(const bf16x8*)&sV[(oi * 16 + lr) * 64 + kk * 32 + kq * 8];
                oacc[oi] = __builtin_amdgcn_mfma_f32_16x16x32_bf16(pf[kk], vfrag, oacc[oi], 0, 0, 0);
            }
        }
        __syncthreads();
    }

#pragma unroll
    for (int r = 0; r < 4; ++r) {
        int row = myq[r];
        float g = ag[row * NHEADS + h];
        float inv = g / l_i[r];
#pragma unroll
        for (int oi = 0; oi < 8; ++oi)
            y[(size_t)row * DMODEL + h * HDIM + oi * 16 + lr] = f2bf(oacc[oi][r] * inv);
    }
}

extern "C" void kernel_launch(void* const* d_in, const int* in_sizes, int n_in,
                              void* d_out, int out_size, void* d_ws, size_t ws_size,
                              hipStream_t stream) {
    (void)in_sizes; (void)n_in; (void)out_size; (void)ws_size;
    const float* x      = (const float*)d_in[0];
    const float* ve     = (const float*)d_in[1];
    const float* qkvo_w = (const float*)d_in[2];
    const float* agw    = (const float*)d_in[3];
    const float* vgw    = (const float*)d_in[4];
    const float* c_fc   = (const float*)d_in[5];
    const float* c_proj = (const float*)d_in[6];
    const float* lam    = (const float*)d_in[7];
    const float* cosb   = (const float*)d_in[8];
    const float* sinb   = (const float*)d_in[9];
    const float* ascale = (const float*)d_in[10];
    const int*   docs   = (const int*)d_in[11];
    const int*   keyoff = (const int*)d_in[12];
    float* out = (float*)d_out;

    char* ws = (char*)d_ws;
    size_t off = 0;
    auto alloc = [&](size_t bytes) {
        char* p = ws + off;
        off += (bytes + 255) & ~(size_t)255;
        return p;
    };
    bf16*  xn     = (bf16*)alloc((size_t)T_SEQ * DMODEL * 2);
    // wqkv+wo+wfc region (67.1 MB); PROJ split-4 partials alias it in step 10.
    char*  wregion = alloc((size_t)3 * DMODEL * DMODEL * 2 +
                           (size_t)DMODEL * DMODEL * 2 +
                           (size_t)FFN_D * DMODEL * 2);
    bf16*  wqkv   = (bf16*)wregion;
    bf16*  wfc    = (bf16*)(wregion + (size_t)4 * DMODEL * DMODEL * 2);
    float* projpart = (float*)wregion;
    bf16*  wprojT = (bf16*)alloc((size_t)DMODEL * FFN_D * 2);
    char*  qkvreg = alloc((size_t)T_SEQ * 3 * DMODEL * 4);    // 50.3 MB region
    bf16*  qkvb   = (bf16*)qkvreg;                            // steps 3-5 (25.2 MB)
    float* opart  = (float*)qkvreg;                           // 2 partials (33.5MB), step 7
    bf16*  hbuf   = (bf16*)qkvreg;                            // steps 9-10 (33.5 MB)
    bf16*  ybuf   = (bf16*)(qkvreg + (size_t)T_SEQ * FFN_D * 2); // steps 6-7 (8.4 MB)
    bf16*  qp     = (bf16*)alloc((size_t)NHEADS * T_SEQ * HDIM * 2);
    bf16*  kp     = (bf16*)alloc((size_t)NHEADS * T_SEQ * HDIM * 2);
    bf16*  vp     = (bf16*)alloc((size_t)NHEADS * HDIM * T_SEQ * 2);
    bf16*  vtmp   = (bf16*)alloc((size_t)T_SEQ * DMODEL * 2);
    float* agate  = (float*)alloc((size_t)T_SEQ * NHEADS * 4);
    float* vgate  = (float*)alloc((size_t)T_SEQ * NHEADS * 4);

    const size_t NN = (size_t)T_SEQ * DMODEL;
    bf16* wo = wqkv + (size_t)3 * DMODEL * DMODEL;   // inside wqkv region (contiguous)

    // 1. xn = rmsnorm(x)
    rmsnorm_k<<<T_SEQ, 256, 0, stream>>>(x, xn);
    // 2. weight converts
    convert_qkvo_k<<<(4 * DMODEL * DMODEL) / 1024, 256, 0, stream>>>(qkvo_w, wqkv, lam);
    convert_k<<<(FFN_D * DMODEL) / 1024, 256, 0, stream>>>(c_fc, wfc, (size_t)FFN_D * DMODEL);
    transpose_convert_k<<<dim3(FFN_D / 32, DMODEL / 32), 256, 0, stream>>>(c_proj, wprojT);
    // 3. qkv = xn @ wqkv^T  (bf16 out)
    gemm_bt<3><<<dim3(3 * DMODEL / 128, T_SEQ / 128, 1), 256, 0, stream>>>(xn, wqkv, nullptr, qkvb, T_SEQ, 3 * DMODEL, DMODEL, DMODEL);
    // 4. gates
    gates_k<<<T_SEQ, 256, 0, stream>>>(xn, agw, vgw, agate, vgate);
    // 5. q/k rmsnorm+rope, v += gate*ve (vtmp T-major)
    qkvproc_k<<<T_SEQ, 256, 0, stream>>>(qkvb, cosb, sinb, ve, vgate, qp, kp, vtmp);
    // 5b. vp = vtmp^T
    transpose16_k<<<dim3(DMODEL / 64, T_SEQ / 64), 256, 0, stream>>>(vtmp, vp, T_SEQ, DMODEL);
    // 6. attention
    fattn_k<<<dim3(T_SEQ / 64, NHEADS), 256, 0, stream>>>(qp, kp, vp, docs, ascale, agate, keyoff, ybuf);
    // 7. attn proj, split-K=2 -> partials
    gemm_bt<0><<<dim3(DMODEL / 128, T_SEQ / 128, 2), 256, 0, stream>>>(ybuf, wo, opart, nullptr, T_SEQ, DMODEL, DMODEL, DMODEL / 2);
    // 8. out = x + p0 + p1 ; xn = rmsnorm(out)
    reduce2_rms_k<<<T_SEQ, 256, 0, stream>>>(x, opart, out, xn);
    // 9. h = relu(xn2 @ wfc^T)^2 -> bf16
    gemm_bt<2><<<dim3(FFN_D / 128, T_SEQ / 128, 1), 256, 0, stream>>>(xn, wfc, nullptr, hbuf, T_SEQ, FFN_D, DMODEL, DMODEL);
    // 10. mlp proj, split-K=4 -> partials; then out += p0..p3
    gemm_bt<0><<<dim3(DMODEL / 128, T_SEQ / 128, 4), 256, 0, stream>>>(hbuf, wprojT, projpart, nullptr, T_SEQ, DMODEL, FFN_D, FFN_D / 4);
    reduce_k<4><<<NN / 1024, 256, 0, stream>>>(out, projpart, out, NN);
}